// Round 2
// baseline (170.331 us; speedup 1.0000x reference)
//
#include <hip/hip_runtime.h>
#include <hip/hip_bf16.h>

// all I/O is float32 (reference is pure jnp.float32)

typedef __attribute__((ext_vector_type(8))) short bf16x8;
typedef __attribute__((ext_vector_type(4))) float f32x4;

// ---- ws layout (f32 element offsets) ----
#define O_WPK   0          // Wpack [tap9][cb16][co64][cin32] bf16 (big convs)
#define O_W51P  147456     // [tap9][co32][ci32] bf16
#define O_W52P  152064
#define O_BNA   156672     // [conv{5a,5c,51,52}][{A,B}][32]
#define O_W8    156928     // w8[2][32], b8 at +64
#define O_PQW   157000     // [4][32], bias at +128
#define O_PKW   157132
#define O_PVW   157264     // [32][32], bias at +1024
#define O_GAM   158320     // p_gamma, c_gamma
#define O_Q     158400     // [b4][cr4][4096] f32
#define O_K     223936     // [b4][cr4][4096] f32
#define O_ENE   453312     // [4][32][32]
#define O_ATT   457408
#define O_F1T   985792     // [b][4096][32] f32 NHWC
#define O_F2T   1510080    // [b][4096][32] f32 NHWC
#define O_V     2034368    // [b][32][4096] bf16
#define O_SAT   2558656    // [b][66][66][32] bf16 padded
#define O_SCT   2837440
// conv-phase overlays (Xt dead before F1T/SAT written):
#define O_XT    461504     // Xt[b4][cb16][66][66][32] bf16 (ends 4922048)
#define O_CP    4922048    // conv partials f32 [ks2][b4][4096pix][64co] (ends 7019200)

__device__ __forceinline__ unsigned short f2b(float f){
  __hip_bfloat16 h = __float2bfloat16(f);
  return *(unsigned short*)&h;
}

// ---------------- prep: pack big conv weights to bf16 [tap][cb][co64][cin32] ----------------
__global__ __launch_bounds__(256) void k_prep_wpack(const float* w5a, const float* w5c, float* ws){
  int id = blockIdx.x*256 + threadIdx.x;   // 294912
  int tap = id >> 15;
  int r = id & 32767;
  int cb = r >> 11;
  int r2 = r & 2047;
  int co = r2 >> 5, ci = r2 & 31;
  int cin = cb*32 + ci;
  float v = (co < 32) ? w5a[co*4608 + cin*9 + tap] : w5c[(co-32)*4608 + cin*9 + tap];
  ((unsigned short*)ws)[id] = f2b(v);
}

__global__ __launch_bounds__(256) void k_prep_misc(
  const float* w51, const float* w52,
  const float* s0,const float* b0,const float* m0,const float* v0,
  const float* s1,const float* b1,const float* m1,const float* v1,
  const float* s2,const float* b2,const float* m2,const float* v2,
  const float* s3,const float* b3,const float* m3,const float* v3,
  const float* w8,const float* b8,
  const float* pqw,const float* pqb,const float* pkw,const float* pkb,
  const float* pvw,const float* pvb,const float* pg,const float* cg,
  float* ws)
{
  int id = blockIdx.x*256 + threadIdx.x;
  if (id >= 20076) return;
  if (id < 9216){ int tap=id>>10, co=(id>>5)&31, ci=id&31;
    ((unsigned short*)(ws + O_W51P))[id] = f2b(w51[co*288 + ci*9 + tap]); return; }
  id -= 9216;
  if (id < 9216){ int tap=id>>10, co=(id>>5)&31, ci=id&31;
    ((unsigned short*)(ws + O_W52P))[id] = f2b(w52[co*288 + ci*9 + tap]); return; }
  id -= 9216;
  if (id < 256){
    int conv = id>>6, ab = (id>>5)&1, c = id&31;
    const float *S,*Bb,*M,*V;
    if (conv==0){S=s0;Bb=b0;M=m0;V=v0;} else if (conv==1){S=s1;Bb=b1;M=m1;V=v1;}
    else if (conv==2){S=s2;Bb=b2;M=m2;V=v2;} else {S=s3;Bb=b3;M=m3;V=v3;}
    float A = S[c] * rsqrtf(V[c] + 1e-5f);
    ws[O_BNA + conv*64 + ab*32 + c] = ab ? (Bb[c] - M[c]*A) : A;
    return; }
  id -= 256;
  if (id < 64){ ws[O_W8+id] = w8[id]; return; } id -= 64;
  if (id < 2){ ws[O_W8+64+id] = b8[id]; return; } id -= 2;
  if (id < 128){ ws[O_PQW+id] = pqw[id]; return; } id -= 128;
  if (id < 4){ ws[O_PQW+128+id] = pqb[id]; return; } id -= 4;
  if (id < 128){ ws[O_PKW+id] = pkw[id]; return; } id -= 128;
  if (id < 4){ ws[O_PKW+128+id] = pkb[id]; return; } id -= 4;
  if (id < 1024){ ws[O_PVW+id] = pvw[id]; return; } id -= 1024;
  if (id < 32){ ws[O_PVW+1024+id] = pvb[id]; return; } id -= 32;
  ws[O_GAM+id] = id ? cg[0] : pg[0];
}

// ---------------- zero Xt borders only (ring of 260 px per (b,cb)) ----------------
__global__ __launch_bounds__(256) void k_zero_xtb(float* __restrict__ ws){
  int i = blockIdx.x*256 + threadIdx.x;   // 66560 uint4
  if (i >= 66560) return;
  int part = i & 3; int j = i >> 2;       // 16640
  int rp = j % 260; int bc = j / 260;     // bc = b*16+cb
  int py, px;
  if (rp < 66){ py = 0; px = rp; }
  else if (rp < 132){ py = 65; px = rp - 66; }
  else if (rp < 196){ py = rp - 131; px = 0; }
  else { py = rp - 195; px = 65; }
  size_t off = (((size_t)bc*66 + py)*66 + px)*32 + part*8;
  *(uint4*)((unsigned short*)(ws + O_XT) + off) = make_uint4(0,0,0,0);
}

// ---------------- zero SA_t / SC_t borders ----------------
__global__ __launch_bounds__(256) void k_zero_sascb(float* __restrict__ ws){
  int i = blockIdx.x*256 + threadIdx.x;   // 8320 uint4
  if (i >= 8320) return;
  int part = i & 3; int j = i >> 2;       // 2080
  int arr = j / 1040; int rem = j - arr*1040;
  int b = rem / 260; int rp = rem % 260;
  int py, px;
  if (rp < 66){ py = 0; px = rp; }
  else if (rp < 132){ py = 65; px = rp - 66; }
  else if (rp < 196){ py = rp - 131; px = 0; }
  else { py = rp - 195; px = 65; }
  size_t off = (((size_t)(b*66) + py)*66 + px)*32 + part*8;
  unsigned short* base = (unsigned short*)(ws + O_SAT + arr*278784);
  *(uint4*)(base + off) = make_uint4(0,0,0,0);
}

// ---------------- NHWC+pad bf16 transform: Xt[b][cb16][66][66][32] ----------------
__global__ __launch_bounds__(256) void k_nhwc(const float* __restrict__ x, float* __restrict__ ws){
  int y = blockIdx.x, ct = blockIdx.y, b = blockIdx.z;  // (64, 8, 4)
  __shared__ unsigned short t16[64][65];
  int tid = threadIdx.x;
  int r0 = tid >> 4, c0 = (tid & 15) * 4;
  const float* xb = x + ((size_t)(b*512 + ct*64))*4096 + y*64;
  #pragma unroll
  for (int i = 0; i < 4; ++i){
    int row = r0 + i*16;
    float4 v = *(const float4*)(xb + (size_t)row*4096 + c0);
    t16[row][c0+0] = f2b(v.x);
    t16[row][c0+1] = f2b(v.y);
    t16[row][c0+2] = f2b(v.z);
    t16[row][c0+3] = f2b(v.w);
  }
  __syncthreads();
  int pixl = tid >> 2, q = tid & 3;
  unsigned short vs[16];
  #pragma unroll
  for (int j = 0; j < 16; ++j) vs[j] = t16[q*16 + j][pixl];
  unsigned u[8];
  #pragma unroll
  for (int j = 0; j < 8; ++j) u[j] = (unsigned)vs[2*j] | ((unsigned)vs[2*j+1] << 16);
  unsigned short* xt = (unsigned short*)(ws + O_XT);
  int cbl = ct*2 + (q>>1);
  size_t off = (((size_t)(b*16 + cbl)*66 + (y+1))*66 + (pixl+1))*32 + (q&1)*16;
  *(uint4*)(xt + off)     = make_uint4(u[0],u[1],u[2],u[3]);
  *(uint4*)(xt + off + 8) = make_uint4(u[4],u[5],u[6],u[7]);
}

// ---------------- big convs as implicit GEMM via MFMA (row-slab staging) ----------------
__global__ __launch_bounds__(256) void k_conv_mfma(float* __restrict__ ws){
  int mb = blockIdx.x;          // b = mb>>6, y = mb&63
  int ks = blockIdx.y;          // cin half
  int b = mb >> 6, y = mb & 63;
  __shared__ unsigned short Bs[198*40];   // [dy*66+px][k32 pad40]
  int tid = threadIdx.x;
  int w = tid >> 6, l = tid & 63;
  f32x4 zero = {0.f,0.f,0.f,0.f};
  f32x4 acc[4] = {zero, zero, zero, zero};
  const unsigned short* wp = (const unsigned short*)ws;
  const unsigned short* xt = (const unsigned short*)(ws + O_XT);
  int arow = w*16 + (l & 15);
  int kq = (l >> 4)*8;
  for (int cb8 = 0; cb8 < 8; ++cb8){
    int cb = ks*8 + cb8;
    const unsigned short* slab = xt + ((size_t)((b*16 + cb)*66 + y))*66*32;
    __syncthreads();
    for (int i = tid; i < 792; i += 256)
      *(uint4*)&Bs[(i>>2)*40 + (i&3)*8] = *(const uint4*)(slab + i*8);
    __syncthreads();
    #pragma unroll
    for (int tap = 0; tap < 9; ++tap){
      int dy = tap/3, dx = tap - dy*3;
      bf16x8 af = *(const bf16x8*)(wp + (size_t)(tap*16 + cb)*2048 + arow*32 + kq);
      #pragma unroll
      for (int pt = 0; pt < 4; ++pt){
        int pix = pt*16 + (l&15) + dx;
        bf16x8 bv = *(const bf16x8*)&Bs[(dy*66 + pix)*40 + kq];
        acc[pt] = __builtin_amdgcn_mfma_f32_16x16x32_bf16(af, bv, acc[pt], 0, 0, 0);
      }
    }
  }
  float* cp = ws + O_CP + ((size_t)(ks*4 + b))*262144;
  int co0 = w*16 + (l>>4)*4;
  #pragma unroll
  for (int pt = 0; pt < 4; ++pt){
    int pix = y*64 + pt*16 + (l & 15);
    *(f32x4*)&cp[(size_t)pix*64 + co0] = acc[pt];
  }
}

// ---------------- reduce partials + BN + ReLU -> F1T, F2T (coalesced) ----------------
__global__ __launch_bounds__(256) void k_reduce_feat(float* __restrict__ ws){
  int id = blockIdx.x*256 + threadIdx.x;     // 1048576 = (b*4096+pix)*64 + co
  float s = ws[O_CP + id] + ws[O_CP + 1048576 + id];
  int co = id & 63; int rest = id >> 6;      // b*4096+pix
  int conv = co >> 5, c = co & 31;
  float A = ws[O_BNA + conv*64 + c], Bb = ws[O_BNA + conv*64 + 32 + c];
  float val = fmaxf(A*s + Bb, 0.f);
  if (conv == 0) ws[O_F1T + (size_t)rest*32 + c] = val;
  else           ws[O_F2T + (size_t)rest*32 + c] = val;
}

// ---------------- q,k,v 1x1 convs (Q,K f32; V bf16) ----------------
// 256 blocks; thread = (part, b, n): part-th cr of q/k + 8 V channels
__global__ __launch_bounds__(256) void k_qkv(float* __restrict__ ws){
  int id = blockIdx.x*256 + threadIdx.x;  // 65536
  int part = id >> 14;                    // 0..3 (uniform per block)
  int nid = id & 16383;                   // b*4096+n
  int b = nid >> 12, n = nid & 4095;
  __shared__ float wq[32], wk[32], wv[8][32];
  int tid = threadIdx.x;
  if (tid < 32){ wq[tid] = ws[O_PQW + part*32 + tid]; wk[tid] = ws[O_PKW + part*32 + tid]; }
  wv[tid>>5][tid&31] = ws[O_PVW + (part*8 + (tid>>5))*32 + (tid&31)];
  __syncthreads();
  const float* fp = ws + O_F1T + (size_t)nid*32;
  float fv[32];
  #pragma unroll
  for (int j=0;j<8;j++){
    float4 v = *(const float4*)(fp + j*4);
    fv[j*4]=v.x; fv[j*4+1]=v.y; fv[j*4+2]=v.z; fv[j*4+3]=v.w;
  }
  float q = ws[O_PQW+128+part], k = ws[O_PKW+128+part];
  #pragma unroll
  for (int c=0;c<32;c++){ q += wq[c]*fv[c]; k += wk[c]*fv[c]; }
  ws[O_Q + (((b<<2)+part)<<12) + n] = q;
  ws[O_K + (((b<<2)+part)<<12) + n] = k;
  unsigned short* vbp = (unsigned short*)(ws + O_V);
  #pragma unroll
  for (int j2=0;j2<8;j2++){
    int c2 = part*8 + j2;
    float v = ws[O_PVW+1024+c2];
    #pragma unroll
    for (int c=0;c<32;c++) v += wv[j2][c]*fv[c];
    vbp[(((b<<5)+c2)<<12) + n] = f2b(v);
  }
}

// ---------------- PAM flash: QK^T (f32 FMA, direct L2 loads, explicit reg ping-pong
//                  prefetch) + fixed-shift softmax + MFMA P@V + ones-trick denom ----------------
// R1 post-mortem: without explicit prefetch the loop is serially latency-bound
// (~1220 cy/iter, VALUBusy 18%). Named A/B register buffers (static indexing) give
// 1-chunk-deep pipelining; 4 waves/SIMD of ~160cy compute hide the ~200cy L2 latency.
__global__ __launch_bounds__(256, 4) void k_pam_flash(float* __restrict__ ws){
  int nt = blockIdx.x;   // 0..255 n-tile of 16
  int b  = blockIdx.y;
  __shared__ float Ss[4][16];
  __shared__ float Os[4][16][36];
  int tid = threadIdx.x;
  int w = tid >> 6, l = tid & 63;
  int nn = l & 15, g = l >> 4;
  int n = (nt<<4) + nn;
  const float LOG2E = 1.44269504f;
  const float BIAS  = -28.8539008f;   // -20 * log2(e); softmax shift-invariant, energies O(+-35)
  float q[4];
  #pragma unroll
  for (int cr=0;cr<4;++cr) q[cr] = ws[O_Q + (((b<<2)+cr)<<12) + n] * LOG2E;
  int mo = g*8;
  int mbase = w*1024 + mo;            // wave w owns m in [w*1024, w*1024+1024)
  const float* kp[4];
  #pragma unroll
  for (int cr=0;cr<4;++cr) kp[cr] = ws + O_K + (((b<<2)+cr)<<12) + mbase;
  const unsigned short* vbp = (const unsigned short*)(ws + O_V);
  const unsigned short* vp0 = vbp + (((b<<5) + nn)<<12) + mbase;
  const unsigned short* vp1 = vbp + (((b<<5) + 16 + nn)<<12) + mbase;
  f32x4 zero = {0.f,0.f,0.f,0.f};
  f32x4 acc0 = zero, acc1 = zero, accS = zero;
  union { bf16x8 v; unsigned short u[8]; } ones;
  #pragma unroll
  for (int j=0;j<8;++j) ones.u[j] = 0x3F80;   // bf16 1.0

  f32x4 kaA[4], kbA[4], kaB[4], kbB[4];
  bf16x8 a0A, a1A, a0B, a1B;

#define PAM_LOAD(KA, KB, A0, A1, M0) \
  { _Pragma("unroll") \
    for (int cr=0;cr<4;++cr){ \
      KA[cr] = *(const f32x4*)(kp[cr] + (M0)); \
      KB[cr] = *(const f32x4*)(kp[cr] + (M0) + 4); \
    } \
    A0 = *(const bf16x8*)(vp0 + (M0)); \
    A1 = *(const bf16x8*)(vp1 + (M0)); }

#define PAM_COMPUTE(KA, KB, A0, A1) \
  { union { bf16x8 v; unsigned short u[8]; } pb; \
    _Pragma("unroll") \
    for (int j=0;j<4;++j){ \
      float e0 = fmaf(q[0], KA[0][j], BIAS); \
      float e1 = fmaf(q[0], KB[0][j], BIAS); \
      _Pragma("unroll") \
      for (int cr=1;cr<4;++cr){ \
        e0 = fmaf(q[cr], KA[cr][j], e0); \
        e1 = fmaf(q[cr], KB[cr][j], e1); \
      } \
      pb.u[j]   = f2b(__builtin_amdgcn_exp2f(e0)); \
      pb.u[j+4] = f2b(__builtin_amdgcn_exp2f(e1)); \
    } \
    acc0 = __builtin_amdgcn_mfma_f32_16x16x32_bf16(A0, pb.v, acc0, 0, 0, 0); \
    acc1 = __builtin_amdgcn_mfma_f32_16x16x32_bf16(A1, pb.v, acc1, 0, 0, 0); \
    accS = __builtin_amdgcn_mfma_f32_16x16x32_bf16(ones.v, pb.v, accS, 0, 0, 0); }

  PAM_LOAD(kaA, kbA, a0A, a1A, 0)
  #pragma unroll 1
  for (int ch2 = 0; ch2 < 16; ++ch2){
    int mA = ch2*64;
    PAM_LOAD(kaB, kbB, a0B, a1B, mA + 32)
    PAM_COMPUTE(kaA, kbA, a0A, a1A)
    if (ch2 < 15){
      PAM_LOAD(kaA, kbA, a0A, a1A, mA + 64)
    }
    PAM_COMPUTE(kaB, kbB, a0B, a1B)
  }
#undef PAM_LOAD
#undef PAM_COMPUTE

  // accS rows are all identical = sum_m P[n][m] over this wave's m-range
  if (l < 16) Ss[w][l] = accS[0];
  #pragma unroll
  for (int r=0;r<4;r++){
    Os[w][nn][g*4 + r]      = acc0[r];
    Os[w][nn][16 + g*4 + r] = acc1[r];
  }
  __syncthreads();
  float gamma = ws[O_GAM];
  unsigned short* sat = (unsigned short*)(ws + O_SAT);
  for (int i = tid; i < 512; i += 256){
    int nn2 = i >> 5, c = i & 31;
    float S = Ss[0][nn2] + Ss[1][nn2] + Ss[2][nn2] + Ss[3][nn2];
    float o = (Os[0][nn2][c] + Os[1][nn2][c] + Os[2][nn2][c] + Os[3][nn2][c]) / S;
    int pix = (nt<<4) + nn2;
    float sa = gamma*o + ws[O_F1T + ((((size_t)b<<12) + pix)<<5) + c];
    int y = pix >> 6, xx = pix & 63;
    sat[(((size_t)((b*66 + y+1)*66 + xx+1))<<5) + c] = f2b(sa);
  }
}

// ---------------- CAM energy ----------------
__global__ __launch_bounds__(256) void k_cam_energy(float* __restrict__ ws){
  int c = blockIdx.x & 31, b = blockIdx.x >> 5;
  int tid = threadIdx.x;
  int w = tid >> 6, lane = tid & 63;
  const float* f = ws + O_F2T + ((size_t)b<<17);   // [n][32]
  float acc[32];
  #pragma unroll
  for (int d=0;d<32;d++) acc[d]=0.f;
  for (int n=tid; n<4096; n+=256){
    const float* fp = f + (size_t)n*32;
    float fv[32];
    #pragma unroll
    for (int j=0;j<8;j++){
      float4 v = *(const float4*)(fp + j*4);
      fv[j*4]=v.x; fv[j*4+1]=v.y; fv[j*4+2]=v.z; fv[j*4+3]=v.w;
    }
    float fc = fv[c];
    #pragma unroll
    for (int d=0;d<32;d++) acc[d] += fc * fv[d];
  }
  __shared__ float part[4][32];
  #pragma unroll
  for (int d=0;d<32;d++){
    float v = acc[d];
    for (int off=32; off; off>>=1) v += __shfl_down(v, off);
    if (lane==0) part[w][d] = v;
    __syncthreads();
    if (tid == 0) ws[O_ENE + (b<<10) + (c<<5) + d] = part[0][d]+part[1][d]+part[2][d]+part[3][d];
    __syncthreads();
  }
}

// ---------------- CAM att (in-block) + out -> SC_t ----------------
// 128 blocks; thread = (half, 128 n): 16 output channels each
__global__ __launch_bounds__(256) void k_cam_out(float* __restrict__ ws){
  int blk = blockIdx.x;            // 128
  int b = blk >> 5;
  int chunk = blk & 31;
  int tid = threadIdx.x;
  int half = tid >> 7;             // 0/1
  int nl = tid & 127;
  int n = (chunk << 7) + nl;
  __shared__ float att[32][33];
  if (tid < 32){
    int c = tid;
    const float* e = ws + O_ENE + (b<<10) + (c<<5);
    float M = -1e30f, mn = 1e30f;
    #pragma unroll
    for (int d=0;d<32;d++){ M = fmaxf(M, e[d]); mn = fminf(mn, e[d]); }
    float mx2 = M - mn;
    float s = 0.f, ex[32];
    #pragma unroll
    for (int d=0;d<32;d++){ ex[d] = __expf((M - e[d]) - mx2); s += ex[d]; }
    float inv = 1.f/s;
    #pragma unroll
    for (int d=0;d<32;d++) att[c][d] = ex[d]*inv;
  }
  __syncthreads();
  const float* fp = ws + O_F2T + (((size_t)b<<12) + n)*32;
  float fv[32];
  #pragma unroll
  for (int j=0;j<8;j++){
    float4 v = *(const float4*)(fp + j*4);
    fv[j*4]=v.x; fv[j*4+1]=v.y; fv[j*4+2]=v.z; fv[j*4+3]=v.w;
  }
  float g = ws[O_GAM+1];
  int c0 = half*16;
  unsigned u[8];
  #pragma unroll
  for (int cp=0; cp<8; ++cp){
    int ca = c0 + 2*cp, cb = ca + 1;
    float o0 = 0.f, o1 = 0.f;
    #pragma unroll
    for (int d=0;d<32;d++){ o0 += att[ca][d]*fv[d]; o1 += att[cb][d]*fv[d]; }
    float r0 = g*o0 + fv[ca], r1 = g*o1 + fv[cb];
    u[cp] = (unsigned)f2b(r0) | ((unsigned)f2b(r1) << 16);
  }
  int y = n >> 6, xcol = n & 63;
  unsigned short* sct = (unsigned short*)(ws + O_SCT);
  size_t base = ((size_t)((b*66 + y+1)*66 + xcol+1))*32 + c0;
  *(uint4*)(sct + base)     = make_uint4(u[0],u[1],u[2],u[3]);
  *(uint4*)(sct + base + 8) = make_uint4(u[4],u[5],u[6],u[7]);
}

// ---------------- fused conv51+conv52 (MFMA) + BN/ReLU + sum + 1x1 conv8 + ReLU ----------------
__global__ __launch_bounds__(256) void k_final_mfma(float* __restrict__ ws, float* __restrict__ out){
  int y = blockIdx.x, b = blockIdx.y;          // (64, 4)
  __shared__ unsigned short Bs[2*3*66*40];     // [conv][dy][pix66][k32 pad40]
  __shared__ float ep[2][2][2][16];            // [wavepair][pt][o][pix16]
  int tid = threadIdx.x;
  int w = tid >> 6, l = tid & 63;
  int g = l >> 4, col = l & 15;
  const unsigned short* sat = (const unsigned short*)(ws + O_SAT);
  const unsigned short* sct = (const unsigned short*)(ws + O_SCT);
  for (int i = tid; i < 1584; i += 256){
    int row = i >> 2, part = i & 3;
    int conv = row / 198; int rr = row - conv*198;
    int dy = rr / 66; int pix = rr - dy*66;
    const unsigned short* src = (conv ? sct : sat) + ((size_t)((b*66 + y + dy)*66 + pix))*32 + part*8;
    *(uint4*)&Bs[(size_t)row*40 + part*8] = *(const uint4*)src;
  }
  __syncthreads();
  int cohalf = w & 1, ptbase = (w >> 1) * 2;
  const unsigned short* wp[2] = { (const unsigned short*)(ws + O_W51P), (const unsigned short*)(ws + O_W52P) };
  f32x4 zero = {0.f,0.f,0.f,0.f};
  f32x4 acc[2][2] = {{zero,zero},{zero,zero}};
  for (int dy = 0; dy < 3; ++dy){
    for (int dx = 0; dx < 3; ++dx){
      int tap = dy*3 + dx;
      #pragma unroll
      for (int conv = 0; conv < 2; ++conv){
        bf16x8 af = *(const bf16x8*)(wp[conv] + tap*1024 + (cohalf*16 + col)*32 + g*8);
        #pragma unroll
        for (int pt = 0; pt < 2; ++pt){
          int pix = (ptbase + pt)*16 + col + dx;
          bf16x8 bv = *(const bf16x8*)&Bs[(size_t)((conv*3 + dy)*66 + pix)*40 + g*8];
          acc[conv][pt] = __builtin_amdgcn_mfma_f32_16x16x32_bf16(af, bv, acc[conv][pt], 0, 0, 0);
        }
      }
    }
  }
  float p0[2], p1[2];
  #pragma unroll
  for (int pt = 0; pt < 2; ++pt){
    float s0 = 0.f, s1 = 0.f;
    #pragma unroll
    for (int r = 0; r < 4; ++r){
      int co = cohalf*16 + g*4 + r;
      float A1 = ws[O_BNA + 2*64 + co], B1 = ws[O_BNA + 2*64 + 32 + co];
      float A2 = ws[O_BNA + 3*64 + co], B2 = ws[O_BNA + 3*64 + 32 + co];
      float fs = fmaxf(A1*acc[0][pt][r] + B1, 0.f) + fmaxf(A2*acc[1][pt][r] + B2, 0.f);
      s0 += ws[O_W8 + co]*fs;
      s1 += ws[O_W8 + 32 + co]*fs;
    }
    s0 += __shfl_xor(s0, 16); s0 += __shfl_xor(s0, 32);
    s1 += __shfl_xor(s1, 16); s1 += __shfl_xor(s1, 32);
    p0[pt] = s0; p1[pt] = s1;
  }
  if (cohalf == 0 && l < 16){
    #pragma unroll
    for (int pt = 0; pt < 2; ++pt){ ep[w>>1][pt][0][l] = p0[pt]; ep[w>>1][pt][1][l] = p1[pt]; }
  }
  __syncthreads();
  if (cohalf == 1 && l < 16){
    float b80 = ws[O_W8 + 64], b81 = ws[O_W8 + 65];
    #pragma unroll
    for (int pt = 0; pt < 2; ++pt){
      int pix = y*64 + (w>>1)*32 + pt*16 + l;
      float o0 = p0[pt] + ep[w>>1][pt][0][l] + b80;
      float o1 = p1[pt] + ep[w>>1][pt][1][l] + b81;
      out[((b*2+0)<<12) + pix] = fmaxf(o0, 0.f);
      out[((b*2+1)<<12) + pix] = fmaxf(o1, 0.f);
    }
  }
}

extern "C" void kernel_launch(void* const* d_in, const int* in_sizes, int n_in,
                              void* d_out, int out_size, void* d_ws, size_t ws_size,
                              hipStream_t stream) {
  const float* x    = (const float*)d_in[0];
  const float* w5a  = (const float*)d_in[1];
  const float* w5c  = (const float*)d_in[18];
  const float* w51  = (const float*)d_in[13];
  const float* w52  = (const float*)d_in[24];
  float* ws = (float*)d_ws;
  float* out = (float*)d_out;

  k_prep_wpack<<<1152, 256, 0, stream>>>(w5a, w5c, ws);
  k_prep_misc<<<79, 256, 0, stream>>>(
      w51, w52,
      (const float*)d_in[2],(const float*)d_in[3],(const float*)d_in[4],(const float*)d_in[5],
      (const float*)d_in[19],(const float*)d_in[20],(const float*)d_in[21],(const float*)d_in[22],
      (const float*)d_in[14],(const float*)d_in[15],(const float*)d_in[16],(const float*)d_in[17],
      (const float*)d_in[25],(const float*)d_in[26],(const float*)d_in[27],(const float*)d_in[28],
      (const float*)d_in[29],(const float*)d_in[30],
      (const float*)d_in[6],(const float*)d_in[7],(const float*)d_in[8],(const float*)d_in[9],
      (const float*)d_in[10],(const float*)d_in[11],(const float*)d_in[12],(const float*)d_in[23],
      ws);
  k_zero_xtb<<<260, 256, 0, stream>>>(ws);
  k_nhwc<<<dim3(64,8,4), 256, 0, stream>>>(x, ws);
  k_conv_mfma<<<dim3(256,2), 256, 0, stream>>>(ws);
  k_reduce_feat<<<4096, 256, 0, stream>>>(ws);
  k_zero_sascb<<<33, 256, 0, stream>>>(ws);
  k_qkv<<<256, 256, 0, stream>>>(ws);
  k_pam_flash<<<dim3(256,4), 256, 0, stream>>>(ws);
  k_cam_energy<<<128, 256, 0, stream>>>(ws);
  k_cam_out<<<128, 256, 0, stream>>>(ws);
  k_final_mfma<<<dim3(64,4), 256, 0, stream>>>(ws, out);
}

// Round 3
// 148.921 us; speedup vs baseline: 1.1438x; 1.1438x over previous
//
#include <hip/hip_runtime.h>
#include <hip/hip_bf16.h>

// all I/O is float32 (reference is pure jnp.float32)

typedef __attribute__((ext_vector_type(8))) short bf16x8;
typedef __attribute__((ext_vector_type(4))) float f32x4;

// ---- ws layout (f32 element offsets) ----
#define O_WPK   0          // Wpack [tap9][cb16][co64][cin32] bf16 (big convs)
#define O_W51P  147456     // [tap9][co32][ci32] bf16
#define O_W52P  152064
#define O_BNA   156672     // [conv{5a,5c,51,52}][{A,B}][32]
#define O_W8    156928     // w8[2][32], b8 at +64
#define O_PQW   157000     // [4][32], bias at +128
#define O_PKW   157132
#define O_PVW   157264     // [32][32], bias at +1024
#define O_GAM   158320     // p_gamma, c_gamma
#define O_Q     158400     // [b4][cr4][4096] f32
#define O_K     223936     // [b4][cr4][4096] f32
#define O_ENE   453312     // [4][32][32]
#define O_ATT   457408
#define O_F1T   985792     // [b][4096][32] f32 NHWC
#define O_F2T   1510080    // [b][4096][32] f32 NHWC
#define O_V     2034368    // [b][32][4096] bf16
#define O_SAT   2558656    // [b][66][66][32] bf16 padded
#define O_SCT   2837440
// conv-phase overlays (Xt dead before F1T/SAT written):
#define O_XT    461504     // Xt[b4][cb16][66][66][32] bf16 (ends 4922048)
#define O_CP    4922048    // conv partials f32 [ks2][b4][4096pix][64co] (ends 7019200)
// PAM-phase overlays (CP dead after k_reduce_feat; XT dead after k_conv_mfma):
#define O_PO    4922048    // PAM partial O [ms4][b4][nt256][nn16][c32] f32 (= old CP, ends 7019200)
#define O_PS    3116224    // PAM partial S [ms4][b4][nt256][nn16] f32 (inside dead XT, after SCT end)

__device__ __forceinline__ unsigned short f2b(float f){
  __hip_bfloat16 h = __float2bfloat16(f);
  return *(unsigned short*)&h;
}

// ---------------- prep: pack big conv weights to bf16 [tap][cb][co64][cin32] ----------------
__global__ __launch_bounds__(256) void k_prep_wpack(const float* w5a, const float* w5c, float* ws){
  int id = blockIdx.x*256 + threadIdx.x;   // 294912
  int tap = id >> 15;
  int r = id & 32767;
  int cb = r >> 11;
  int r2 = r & 2047;
  int co = r2 >> 5, ci = r2 & 31;
  int cin = cb*32 + ci;
  float v = (co < 32) ? w5a[co*4608 + cin*9 + tap] : w5c[(co-32)*4608 + cin*9 + tap];
  ((unsigned short*)ws)[id] = f2b(v);
}

__global__ __launch_bounds__(256) void k_prep_misc(
  const float* w51, const float* w52,
  const float* s0,const float* b0,const float* m0,const float* v0,
  const float* s1,const float* b1,const float* m1,const float* v1,
  const float* s2,const float* b2,const float* m2,const float* v2,
  const float* s3,const float* b3,const float* m3,const float* v3,
  const float* w8,const float* b8,
  const float* pqw,const float* pqb,const float* pkw,const float* pkb,
  const float* pvw,const float* pvb,const float* pg,const float* cg,
  float* ws)
{
  int id = blockIdx.x*256 + threadIdx.x;
  if (id >= 20076) return;
  if (id < 9216){ int tap=id>>10, co=(id>>5)&31, ci=id&31;
    ((unsigned short*)(ws + O_W51P))[id] = f2b(w51[co*288 + ci*9 + tap]); return; }
  id -= 9216;
  if (id < 9216){ int tap=id>>10, co=(id>>5)&31, ci=id&31;
    ((unsigned short*)(ws + O_W52P))[id] = f2b(w52[co*288 + ci*9 + tap]); return; }
  id -= 9216;
  if (id < 256){
    int conv = id>>6, ab = (id>>5)&1, c = id&31;
    const float *S,*Bb,*M,*V;
    if (conv==0){S=s0;Bb=b0;M=m0;V=v0;} else if (conv==1){S=s1;Bb=b1;M=m1;V=v1;}
    else if (conv==2){S=s2;Bb=b2;M=m2;V=v2;} else {S=s3;Bb=b3;M=m3;V=v3;}
    float A = S[c] * rsqrtf(V[c] + 1e-5f);
    ws[O_BNA + conv*64 + ab*32 + c] = ab ? (Bb[c] - M[c]*A) : A;
    return; }
  id -= 256;
  if (id < 64){ ws[O_W8+id] = w8[id]; return; } id -= 64;
  if (id < 2){ ws[O_W8+64+id] = b8[id]; return; } id -= 2;
  if (id < 128){ ws[O_PQW+id] = pqw[id]; return; } id -= 128;
  if (id < 4){ ws[O_PQW+128+id] = pqb[id]; return; } id -= 4;
  if (id < 128){ ws[O_PKW+id] = pkw[id]; return; } id -= 128;
  if (id < 4){ ws[O_PKW+128+id] = pkb[id]; return; } id -= 4;
  if (id < 1024){ ws[O_PVW+id] = pvw[id]; return; } id -= 1024;
  if (id < 32){ ws[O_PVW+1024+id] = pvb[id]; return; } id -= 32;
  ws[O_GAM+id] = id ? cg[0] : pg[0];
}

// ---------------- zero Xt borders only (ring of 260 px per (b,cb)) ----------------
__global__ __launch_bounds__(256) void k_zero_xtb(float* __restrict__ ws){
  int i = blockIdx.x*256 + threadIdx.x;   // 66560 uint4
  if (i >= 66560) return;
  int part = i & 3; int j = i >> 2;       // 16640
  int rp = j % 260; int bc = j / 260;     // bc = b*16+cb
  int py, px;
  if (rp < 66){ py = 0; px = rp; }
  else if (rp < 132){ py = 65; px = rp - 66; }
  else if (rp < 196){ py = rp - 131; px = 0; }
  else { py = rp - 195; px = 65; }
  size_t off = (((size_t)bc*66 + py)*66 + px)*32 + part*8;
  *(uint4*)((unsigned short*)(ws + O_XT) + off) = make_uint4(0,0,0,0);
}

// ---------------- zero SA_t / SC_t borders ----------------
__global__ __launch_bounds__(256) void k_zero_sascb(float* __restrict__ ws){
  int i = blockIdx.x*256 + threadIdx.x;   // 8320 uint4
  if (i >= 8320) return;
  int part = i & 3; int j = i >> 2;       // 2080
  int arr = j / 1040; int rem = j - arr*1040;
  int b = rem / 260; int rp = rem % 260;
  int py, px;
  if (rp < 66){ py = 0; px = rp; }
  else if (rp < 132){ py = 65; px = rp - 66; }
  else if (rp < 196){ py = rp - 131; px = 0; }
  else { py = rp - 195; px = 65; }
  size_t off = (((size_t)(b*66) + py)*66 + px)*32 + part*8;
  unsigned short* base = (unsigned short*)(ws + O_SAT + arr*278784);
  *(uint4*)(base + off) = make_uint4(0,0,0,0);
}

// ---------------- NHWC+pad bf16 transform: Xt[b][cb16][66][66][32] ----------------
__global__ __launch_bounds__(256) void k_nhwc(const float* __restrict__ x, float* __restrict__ ws){
  int y = blockIdx.x, ct = blockIdx.y, b = blockIdx.z;  // (64, 8, 4)
  __shared__ unsigned short t16[64][65];
  int tid = threadIdx.x;
  int r0 = tid >> 4, c0 = (tid & 15) * 4;
  const float* xb = x + ((size_t)(b*512 + ct*64))*4096 + y*64;
  #pragma unroll
  for (int i = 0; i < 4; ++i){
    int row = r0 + i*16;
    float4 v = *(const float4*)(xb + (size_t)row*4096 + c0);
    t16[row][c0+0] = f2b(v.x);
    t16[row][c0+1] = f2b(v.y);
    t16[row][c0+2] = f2b(v.z);
    t16[row][c0+3] = f2b(v.w);
  }
  __syncthreads();
  int pixl = tid >> 2, q = tid & 3;
  unsigned short vs[16];
  #pragma unroll
  for (int j = 0; j < 16; ++j) vs[j] = t16[q*16 + j][pixl];
  unsigned u[8];
  #pragma unroll
  for (int j = 0; j < 8; ++j) u[j] = (unsigned)vs[2*j] | ((unsigned)vs[2*j+1] << 16);
  unsigned short* xt = (unsigned short*)(ws + O_XT);
  int cbl = ct*2 + (q>>1);
  size_t off = (((size_t)(b*16 + cbl)*66 + (y+1))*66 + (pixl+1))*32 + (q&1)*16;
  *(uint4*)(xt + off)     = make_uint4(u[0],u[1],u[2],u[3]);
  *(uint4*)(xt + off + 8) = make_uint4(u[4],u[5],u[6],u[7]);
}

// ---------------- big convs as implicit GEMM via MFMA (row-slab staging) ----------------
__global__ __launch_bounds__(256) void k_conv_mfma(float* __restrict__ ws){
  int mb = blockIdx.x;          // b = mb>>6, y = mb&63
  int ks = blockIdx.y;          // cin half
  int b = mb >> 6, y = mb & 63;
  __shared__ unsigned short Bs[198*40];   // [dy*66+px][k32 pad40]
  int tid = threadIdx.x;
  int w = tid >> 6, l = tid & 63;
  f32x4 zero = {0.f,0.f,0.f,0.f};
  f32x4 acc[4] = {zero, zero, zero, zero};
  const unsigned short* wp = (const unsigned short*)ws;
  const unsigned short* xt = (const unsigned short*)(ws + O_XT);
  int arow = w*16 + (l & 15);
  int kq = (l >> 4)*8;
  for (int cb8 = 0; cb8 < 8; ++cb8){
    int cb = ks*8 + cb8;
    const unsigned short* slab = xt + ((size_t)((b*16 + cb)*66 + y))*66*32;
    __syncthreads();
    for (int i = tid; i < 792; i += 256)
      *(uint4*)&Bs[(i>>2)*40 + (i&3)*8] = *(const uint4*)(slab + i*8);
    __syncthreads();
    #pragma unroll
    for (int tap = 0; tap < 9; ++tap){
      int dy = tap/3, dx = tap - dy*3;
      bf16x8 af = *(const bf16x8*)(wp + (size_t)(tap*16 + cb)*2048 + arow*32 + kq);
      #pragma unroll
      for (int pt = 0; pt < 4; ++pt){
        int pix = pt*16 + (l&15) + dx;
        bf16x8 bv = *(const bf16x8*)&Bs[(dy*66 + pix)*40 + kq];
        acc[pt] = __builtin_amdgcn_mfma_f32_16x16x32_bf16(af, bv, acc[pt], 0, 0, 0);
      }
    }
  }
  float* cp = ws + O_CP + ((size_t)(ks*4 + b))*262144;
  int co0 = w*16 + (l>>4)*4;
  #pragma unroll
  for (int pt = 0; pt < 4; ++pt){
    int pix = y*64 + pt*16 + (l & 15);
    *(f32x4*)&cp[(size_t)pix*64 + co0] = acc[pt];
  }
}

// ---------------- reduce partials + BN + ReLU -> F1T, F2T (coalesced) ----------------
__global__ __launch_bounds__(256) void k_reduce_feat(float* __restrict__ ws){
  int id = blockIdx.x*256 + threadIdx.x;     // 1048576 = (b*4096+pix)*64 + co
  float s = ws[O_CP + id] + ws[O_CP + 1048576 + id];
  int co = id & 63; int rest = id >> 6;      // b*4096+pix
  int conv = co >> 5, c = co & 31;
  float A = ws[O_BNA + conv*64 + c], Bb = ws[O_BNA + conv*64 + 32 + c];
  float val = fmaxf(A*s + Bb, 0.f);
  if (conv == 0) ws[O_F1T + (size_t)rest*32 + c] = val;
  else           ws[O_F2T + (size_t)rest*32 + c] = val;
}

// ---------------- q,k,v 1x1 convs (Q,K f32; V bf16) ----------------
// 256 blocks; thread = (part, b, n): part-th cr of q/k + 8 V channels
__global__ __launch_bounds__(256) void k_qkv(float* __restrict__ ws){
  int id = blockIdx.x*256 + threadIdx.x;  // 65536
  int part = id >> 14;                    // 0..3 (uniform per block)
  int nid = id & 16383;                   // b*4096+n
  int b = nid >> 12, n = nid & 4095;
  __shared__ float wq[32], wk[32], wv[8][32];
  int tid = threadIdx.x;
  if (tid < 32){ wq[tid] = ws[O_PQW + part*32 + tid]; wk[tid] = ws[O_PKW + part*32 + tid]; }
  wv[tid>>5][tid&31] = ws[O_PVW + (part*8 + (tid>>5))*32 + (tid&31)];
  __syncthreads();
  const float* fp = ws + O_F1T + (size_t)nid*32;
  float fv[32];
  #pragma unroll
  for (int j=0;j<8;j++){
    float4 v = *(const float4*)(fp + j*4);
    fv[j*4]=v.x; fv[j*4+1]=v.y; fv[j*4+2]=v.z; fv[j*4+3]=v.w;
  }
  float q = ws[O_PQW+128+part], k = ws[O_PKW+128+part];
  #pragma unroll
  for (int c=0;c<32;c++){ q += wq[c]*fv[c]; k += wk[c]*fv[c]; }
  ws[O_Q + (((b<<2)+part)<<12) + n] = q;
  ws[O_K + (((b<<2)+part)<<12) + n] = k;
  unsigned short* vbp = (unsigned short*)(ws + O_V);
  #pragma unroll
  for (int j2=0;j2<8;j2++){
    int c2 = part*8 + j2;
    float v = ws[O_PVW+1024+c2];
    #pragma unroll
    for (int c=0;c<32;c++) v += wv[j2][c]*fv[c];
    vbp[(((b<<5)+c2)<<12) + n] = f2b(v);
  }
}

// ---------------- PAM flash, m-split x4: QK^T + fixed-shift exp2 softmax + MFMA P@V
// Proven LDS ping-pong schedule (prefetch regs at top, ds_write at bottom keeps loads
// in flight across compute — compiler can't sink them). Grid 4096 blocks fixes the
// occupancy cap (was grid-limited to 4 blocks/CU). Partial (O,S) -> ws; k_pam_fin combines.
__global__ __launch_bounds__(256, 6) void k_pam_flash(float* __restrict__ ws){
  int nt = blockIdx.x;   // 0..255 n-tile of 16
  int b  = blockIdx.y;   // 0..3
  int ms = blockIdx.z;   // 0..3 m-split
  __shared__ float Ks[2][4][4][32];            // [buf][wave][cr][m32]   4 KB
  __shared__ unsigned short Vs[2][4][1280];    // [buf][wave][c*40+m]   20 KB
  __shared__ float Ss[4][16];
  int tid = threadIdx.x;
  int w = tid >> 6, l = tid & 63;
  int nn = l & 15, g = l >> 4;
  int n = (nt<<4) + nn;
  const float LOG2E = 1.44269504f;
  const float BIAS  = -28.8539008f;   // -20*log2(e); fixed shift, energies O(+-35)
  float q0 = ws[O_Q + (((b<<2)+0)<<12) + n] * LOG2E;
  float q1 = ws[O_Q + (((b<<2)+1)<<12) + n] * LOG2E;
  float q2 = ws[O_Q + (((b<<2)+2)<<12) + n] * LOG2E;
  float q3 = ws[O_Q + (((b<<2)+3)<<12) + n] * LOG2E;
  const unsigned short* vb = (const unsigned short*)(ws + O_V);
  int e0 = l*2, cr_s = e0 >> 5, mm_s = e0 & 31;
  int c_s = l >> 1, mh_s = (l & 1) * 16;
  int mbase = ms*1024 + w*256;        // wave handles m in [mbase, mbase+256), 8 chunks
  const float* ksrc = ws + O_K + (((b<<2)+cr_s)<<12) + mbase + mm_s;
  const unsigned short* vsrc = vb + (((b<<5)+c_s)<<12) + mbase + mh_s;
  int mo = g*8;
  f32x4 zero = {0.f,0.f,0.f,0.f};
  f32x4 acc0 = zero, acc1 = zero, accS = zero;
  union { bf16x8 v; unsigned short u[8]; } ones;
  #pragma unroll
  for (int j=0;j<8;++j) ones.u[j] = 0x3F80;   // bf16 1.0
  float2 kreg = *(const float2*)(ksrc);
  uint4 vr0 = *(const uint4*)(vsrc);
  uint4 vr1 = *(const uint4*)(vsrc + 8);
  *(float2*)&Ks[0][w][cr_s][mm_s] = kreg;
  *(uint4*)&Vs[0][w][c_s*40 + mh_s] = vr0;
  *(uint4*)&Vs[0][w][c_s*40 + mh_s + 8] = vr1;
  for (int ch = 0; ch < 8; ++ch){
    int buf = ch & 1;
    if (ch < 7){
      int m0n = (ch+1)*32;
      kreg = *(const float2*)(ksrc + m0n);
      vr0 = *(const uint4*)(vsrc + m0n);
      vr1 = *(const uint4*)(vsrc + m0n + 8);
    }
    float e[8];
    {
      float4 ka = *(const float4*)&Ks[buf][w][0][mo];
      float4 kb = *(const float4*)&Ks[buf][w][0][mo+4];
      e[0]=fmaf(q0,ka.x,BIAS); e[1]=fmaf(q0,ka.y,BIAS); e[2]=fmaf(q0,ka.z,BIAS); e[3]=fmaf(q0,ka.w,BIAS);
      e[4]=fmaf(q0,kb.x,BIAS); e[5]=fmaf(q0,kb.y,BIAS); e[6]=fmaf(q0,kb.z,BIAS); e[7]=fmaf(q0,kb.w,BIAS);
      ka = *(const float4*)&Ks[buf][w][1][mo]; kb = *(const float4*)&Ks[buf][w][1][mo+4];
      e[0]=fmaf(q1,ka.x,e[0]); e[1]=fmaf(q1,ka.y,e[1]); e[2]=fmaf(q1,ka.z,e[2]); e[3]=fmaf(q1,ka.w,e[3]);
      e[4]=fmaf(q1,kb.x,e[4]); e[5]=fmaf(q1,kb.y,e[5]); e[6]=fmaf(q1,kb.z,e[6]); e[7]=fmaf(q1,kb.w,e[7]);
      ka = *(const float4*)&Ks[buf][w][2][mo]; kb = *(const float4*)&Ks[buf][w][2][mo+4];
      e[0]=fmaf(q2,ka.x,e[0]); e[1]=fmaf(q2,ka.y,e[1]); e[2]=fmaf(q2,ka.z,e[2]); e[3]=fmaf(q2,ka.w,e[3]);
      e[4]=fmaf(q2,kb.x,e[4]); e[5]=fmaf(q2,kb.y,e[5]); e[6]=fmaf(q2,kb.z,e[6]); e[7]=fmaf(q2,kb.w,e[7]);
      ka = *(const float4*)&Ks[buf][w][3][mo]; kb = *(const float4*)&Ks[buf][w][3][mo+4];
      e[0]=fmaf(q3,ka.x,e[0]); e[1]=fmaf(q3,ka.y,e[1]); e[2]=fmaf(q3,ka.z,e[2]); e[3]=fmaf(q3,ka.w,e[3]);
      e[4]=fmaf(q3,kb.x,e[4]); e[5]=fmaf(q3,kb.y,e[5]); e[6]=fmaf(q3,kb.z,e[6]); e[7]=fmaf(q3,kb.w,e[7]);
    }
    union { bf16x8 v; unsigned short u[8]; } pb;
    #pragma unroll
    for (int j=0;j<8;j++) pb.u[j] = f2b(__builtin_amdgcn_exp2f(e[j]));
    bf16x8 a0 = *(const bf16x8*)&Vs[buf][w][nn*40 + mo];
    bf16x8 a1 = *(const bf16x8*)&Vs[buf][w][(16+nn)*40 + mo];
    acc0 = __builtin_amdgcn_mfma_f32_16x16x32_bf16(a0, pb.v, acc0, 0, 0, 0);
    acc1 = __builtin_amdgcn_mfma_f32_16x16x32_bf16(a1, pb.v, acc1, 0, 0, 0);
    accS = __builtin_amdgcn_mfma_f32_16x16x32_bf16(ones.v, pb.v, accS, 0, 0, 0);
    if (ch < 7){
      int nb = buf ^ 1;
      *(float2*)&Ks[nb][w][cr_s][mm_s] = kreg;
      *(uint4*)&Vs[nb][w][c_s*40 + mh_s] = vr0;
      *(uint4*)&Vs[nb][w][c_s*40 + mh_s + 8] = vr1;
    }
  }
  // accS rows identical = sum_m P[n][m] over this wave's m-range
  if (l < 16) Ss[w][l] = accS[0];
  __syncthreads();                       // all waves done reading Vs
  float* Os = (float*)&Vs[0][0][0];      // alias: [4 wave][16 nn][36] f32 (9.2 KB < 20 KB)
  #pragma unroll
  for (int r=0;r<4;r++){
    Os[(w*16+nn)*36 + g*4 + r]      = acc0[r];
    Os[(w*16+nn)*36 + 16 + g*4 + r] = acc1[r];
  }
  __syncthreads();
  float* PO = ws + O_PO + ((size_t)((ms*4+b)*256+nt))*512;
  for (int i = tid; i < 512; i += 256){
    int nn2 = i >> 5, c = i & 31;
    PO[i] = Os[nn2*36 + c] + Os[(16+nn2)*36 + c] + Os[(32+nn2)*36 + c] + Os[(48+nn2)*36 + c];
  }
  if (tid < 16)
    ws[O_PS + ((ms*4+b)*256+nt)*16 + tid] = Ss[0][tid]+Ss[1][tid]+Ss[2][tid]+Ss[3][tid];
}

// ---------------- PAM finalize: combine 4 m-split partials, divide, residual -> SA_t ----------------
__global__ __launch_bounds__(256) void k_pam_fin(float* __restrict__ ws){
  int id = blockIdx.x*256 + threadIdx.x;   // 524288 = (b*4096+n)*32 + c
  int c = id & 31;
  int n = (id >> 5) & 4095;
  int b = id >> 17;
  int nt = n >> 4, nn = n & 15;
  int pbase = ((b*256+nt)*512) + nn*32 + c;
  int sbase = (b*256+nt)*16 + nn;
  float O = ws[O_PO + pbase] + ws[O_PO + 524288 + pbase]
          + ws[O_PO + 1048576 + pbase] + ws[O_PO + 1572864 + pbase];
  float S = ws[O_PS + sbase] + ws[O_PS + 16384 + sbase]
          + ws[O_PS + 32768 + sbase] + ws[O_PS + 49152 + sbase];
  float sa = ws[O_GAM]*(O/S) + ws[O_F1T + id];
  int y = n >> 6, xx = n & 63;
  ((unsigned short*)(ws + O_SAT))[(((size_t)((b*66 + y+1)*66 + xx+1))<<5) + c] = f2b(sa);
}

// ---------------- CAM energy ----------------
__global__ __launch_bounds__(256) void k_cam_energy(float* __restrict__ ws){
  int c = blockIdx.x & 31, b = blockIdx.x >> 5;
  int tid = threadIdx.x;
  int w = tid >> 6, lane = tid & 63;
  const float* f = ws + O_F2T + ((size_t)b<<17);   // [n][32]
  float acc[32];
  #pragma unroll
  for (int d=0;d<32;d++) acc[d]=0.f;
  for (int n=tid; n<4096; n+=256){
    const float* fp = f + (size_t)n*32;
    float fv[32];
    #pragma unroll
    for (int j=0;j<8;j++){
      float4 v = *(const float4*)(fp + j*4);
      fv[j*4]=v.x; fv[j*4+1]=v.y; fv[j*4+2]=v.z; fv[j*4+3]=v.w;
    }
    float fc = fv[c];
    #pragma unroll
    for (int d=0;d<32;d++) acc[d] += fc * fv[d];
  }
  __shared__ float part[4][32];
  #pragma unroll
  for (int d=0;d<32;d++){
    float v = acc[d];
    for (int off=32; off; off>>=1) v += __shfl_down(v, off);
    if (lane==0) part[w][d] = v;
    __syncthreads();
    if (tid == 0) ws[O_ENE + (b<<10) + (c<<5) + d] = part[0][d]+part[1][d]+part[2][d]+part[3][d];
    __syncthreads();
  }
}

// ---------------- CAM att (in-block) + out -> SC_t ----------------
// 128 blocks; thread = (half, 128 n): 16 output channels each
__global__ __launch_bounds__(256) void k_cam_out(float* __restrict__ ws){
  int blk = blockIdx.x;            // 128
  int b = blk >> 5;
  int chunk = blk & 31;
  int tid = threadIdx.x;
  int half = tid >> 7;             // 0/1
  int nl = tid & 127;
  int n = (chunk << 7) + nl;
  __shared__ float att[32][33];
  if (tid < 32){
    int c = tid;
    const float* e = ws + O_ENE + (b<<10) + (c<<5);
    float M = -1e30f, mn = 1e30f;
    #pragma unroll
    for (int d=0;d<32;d++){ M = fmaxf(M, e[d]); mn = fminf(mn, e[d]); }
    float mx2 = M - mn;
    float s = 0.f, ex[32];
    #pragma unroll
    for (int d=0;d<32;d++){ ex[d] = __expf((M - e[d]) - mx2); s += ex[d]; }
    float inv = 1.f/s;
    #pragma unroll
    for (int d=0;d<32;d++) att[c][d] = ex[d]*inv;
  }
  __syncthreads();
  const float* fp = ws + O_F2T + (((size_t)b<<12) + n)*32;
  float fv[32];
  #pragma unroll
  for (int j=0;j<8;j++){
    float4 v = *(const float4*)(fp + j*4);
    fv[j*4]=v.x; fv[j*4+1]=v.y; fv[j*4+2]=v.z; fv[j*4+3]=v.w;
  }
  float g = ws[O_GAM+1];
  int c0 = half*16;
  unsigned u[8];
  #pragma unroll
  for (int cp=0; cp<8; ++cp){
    int ca = c0 + 2*cp, cb = ca + 1;
    float o0 = 0.f, o1 = 0.f;
    #pragma unroll
    for (int d=0;d<32;d++){ o0 += att[ca][d]*fv[d]; o1 += att[cb][d]*fv[d]; }
    float r0 = g*o0 + fv[ca], r1 = g*o1 + fv[cb];
    u[cp] = (unsigned)f2b(r0) | ((unsigned)f2b(r1) << 16);
  }
  int y = n >> 6, xcol = n & 63;
  unsigned short* sct = (unsigned short*)(ws + O_SCT);
  size_t base = ((size_t)((b*66 + y+1)*66 + xcol+1))*32 + c0;
  *(uint4*)(sct + base)     = make_uint4(u[0],u[1],u[2],u[3]);
  *(uint4*)(sct + base + 8) = make_uint4(u[4],u[5],u[6],u[7]);
}

// ---------------- fused conv51+conv52 (MFMA) + BN/ReLU + sum + 1x1 conv8 + ReLU ----------------
__global__ __launch_bounds__(256) void k_final_mfma(float* __restrict__ ws, float* __restrict__ out){
  int y = blockIdx.x, b = blockIdx.y;          // (64, 4)
  __shared__ unsigned short Bs[2*3*66*40];     // [conv][dy][pix66][k32 pad40]
  __shared__ float ep[2][2][2][16];            // [wavepair][pt][o][pix16]
  int tid = threadIdx.x;
  int w = tid >> 6, l = tid & 63;
  int g = l >> 4, col = l & 15;
  const unsigned short* sat = (const unsigned short*)(ws + O_SAT);
  const unsigned short* sct = (const unsigned short*)(ws + O_SCT);
  for (int i = tid; i < 1584; i += 256){
    int row = i >> 2, part = i & 3;
    int conv = row / 198; int rr = row - conv*198;
    int dy = rr / 66; int pix = rr - dy*66;
    const unsigned short* src = (conv ? sct : sat) + ((size_t)((b*66 + y + dy)*66 + pix))*32 + part*8;
    *(uint4*)&Bs[(size_t)row*40 + part*8] = *(const uint4*)src;
  }
  __syncthreads();
  int cohalf = w & 1, ptbase = (w >> 1) * 2;
  const unsigned short* wp[2] = { (const unsigned short*)(ws + O_W51P), (const unsigned short*)(ws + O_W52P) };
  f32x4 zero = {0.f,0.f,0.f,0.f};
  f32x4 acc[2][2] = {{zero,zero},{zero,zero}};
  for (int dy = 0; dy < 3; ++dy){
    for (int dx = 0; dx < 3; ++dx){
      int tap = dy*3 + dx;
      #pragma unroll
      for (int conv = 0; conv < 2; ++conv){
        bf16x8 af = *(const bf16x8*)(wp[conv] + tap*1024 + (cohalf*16 + col)*32 + g*8);
        #pragma unroll
        for (int pt = 0; pt < 2; ++pt){
          int pix = (ptbase + pt)*16 + col + dx;
          bf16x8 bv = *(const bf16x8*)&Bs[(size_t)((conv*3 + dy)*66 + pix)*40 + g*8];
          acc[conv][pt] = __builtin_amdgcn_mfma_f32_16x16x32_bf16(af, bv, acc[conv][pt], 0, 0, 0);
        }
      }
    }
  }
  float p0[2], p1[2];
  #pragma unroll
  for (int pt = 0; pt < 2; ++pt){
    float s0 = 0.f, s1 = 0.f;
    #pragma unroll
    for (int r = 0; r < 4; ++r){
      int co = cohalf*16 + g*4 + r;
      float A1 = ws[O_BNA + 2*64 + co], B1 = ws[O_BNA + 2*64 + 32 + co];
      float A2 = ws[O_BNA + 3*64 + co], B2 = ws[O_BNA + 3*64 + 32 + co];
      float fs = fmaxf(A1*acc[0][pt][r] + B1, 0.f) + fmaxf(A2*acc[1][pt][r] + B2, 0.f);
      s0 += ws[O_W8 + co]*fs;
      s1 += ws[O_W8 + 32 + co]*fs;
    }
    s0 += __shfl_xor(s0, 16); s0 += __shfl_xor(s0, 32);
    s1 += __shfl_xor(s1, 16); s1 += __shfl_xor(s1, 32);
    p0[pt] = s0; p1[pt] = s1;
  }
  if (cohalf == 0 && l < 16){
    #pragma unroll
    for (int pt = 0; pt < 2; ++pt){ ep[w>>1][pt][0][l] = p0[pt]; ep[w>>1][pt][1][l] = p1[pt]; }
  }
  __syncthreads();
  if (cohalf == 1 && l < 16){
    float b80 = ws[O_W8 + 64], b81 = ws[O_W8 + 65];
    #pragma unroll
    for (int pt = 0; pt < 2; ++pt){
      int pix = y*64 + (w>>1)*32 + pt*16 + l;
      float o0 = p0[pt] + ep[w>>1][pt][0][l] + b80;
      float o1 = p1[pt] + ep[w>>1][pt][1][l] + b81;
      out[((b*2+0)<<12) + pix] = fmaxf(o0, 0.f);
      out[((b*2+1)<<12) + pix] = fmaxf(o1, 0.f);
    }
  }
}

extern "C" void kernel_launch(void* const* d_in, const int* in_sizes, int n_in,
                              void* d_out, int out_size, void* d_ws, size_t ws_size,
                              hipStream_t stream) {
  const float* x    = (const float*)d_in[0];
  const float* w5a  = (const float*)d_in[1];
  const float* w5c  = (const float*)d_in[18];
  const float* w51  = (const float*)d_in[13];
  const float* w52  = (const float*)d_in[24];
  float* ws = (float*)d_ws;
  float* out = (float*)d_out;

  k_prep_wpack<<<1152, 256, 0, stream>>>(w5a, w5c, ws);
  k_prep_misc<<<79, 256, 0, stream>>>(
      w51, w52,
      (const float*)d_in[2],(const float*)d_in[3],(const float*)d_in[4],(const float*)d_in[5],
      (const float*)d_in[19],(const float*)d_in[20],(const float*)d_in[21],(const float*)d_in[22],
      (const float*)d_in[14],(const float*)d_in[15],(const float*)d_in[16],(const float*)d_in[17],
      (const float*)d_in[25],(const float*)d_in[26],(const float*)d_in[27],(const float*)d_in[28],
      (const float*)d_in[29],(const float*)d_in[30],
      (const float*)d_in[6],(const float*)d_in[7],(const float*)d_in[8],(const float*)d_in[9],
      (const float*)d_in[10],(const float*)d_in[11],(const float*)d_in[12],(const float*)d_in[23],
      ws);
  k_zero_xtb<<<260, 256, 0, stream>>>(ws);
  k_nhwc<<<dim3(64,8,4), 256, 0, stream>>>(x, ws);
  k_conv_mfma<<<dim3(256,2), 256, 0, stream>>>(ws);
  k_reduce_feat<<<4096, 256, 0, stream>>>(ws);
  k_zero_sascb<<<33, 256, 0, stream>>>(ws);
  k_qkv<<<256, 256, 0, stream>>>(ws);
  k_pam_flash<<<dim3(256,4,4), 256, 0, stream>>>(ws);
  k_pam_fin<<<2048, 256, 0, stream>>>(ws);
  k_cam_energy<<<128, 256, 0, stream>>>(ws);
  k_cam_out<<<128, 256, 0, stream>>>(ws);
  k_final_mfma<<<dim3(64,4), 256, 0, stream>>>(ws, out);
}

// Round 4
// 117.085 us; speedup vs baseline: 1.4548x; 1.2719x over previous
//
#include <hip/hip_runtime.h>
#include <hip/hip_bf16.h>

// all I/O is float32 (reference is pure jnp.float32)

typedef __attribute__((ext_vector_type(8))) short bf16x8;
typedef __attribute__((ext_vector_type(4))) float f32x4;

// ---- ws layout (f32 element offsets) ----
#define O_WPK   0          // Wpack [tap9][cb16][co64][cin32] bf16 (big convs)
#define O_W51P  147456     // [tap9][co32][ci32] bf16
#define O_W52P  152064
#define O_BNA   156672     // [conv{5a,5c,51,52}][{A,B}][32]
#define O_W8    156928     // w8[2][32], b8 at +64
#define O_PQW   157000     // [4][32], bias at +128
#define O_PKW   157132
#define O_PVW   157264     // [32][32], bias at +1024
#define O_GAM   158320     // p_gamma, c_gamma
#define O_Q     158400     // [b4][cr4][4096] f32
#define O_K     223936     // [b4][cr4][4096] f32
#define O_ENE   453312     // [4][32][32]
#define O_PE    457408     // CAM energy partials [b4][ch64][32][32] f32 (ends 719552)
#define O_F1T   985792     // [b][4096][32] f32 NHWC
#define O_F2T   1510080    // [b][4096][32] f32 NHWC
#define O_V     2034368    // [b][32][4096] bf16
#define O_SAT   2558656    // [b][66][66][32] bf16 padded
#define O_SCT   2837440
// conv-phase overlays (Xt dead before F1T/SAT written):
#define O_XT    461504     // Xt[b4][cb16][66][66][32] bf16 (ends 4922048)
#define O_CP    4922048    // conv partials f32 [ks4][b4][4096pix][64co] (ends 9116352)
// PAM-phase overlays (CP dead after k_reduce_feat; XT dead after k_conv_mfma):
#define O_PO    4922048    // PAM partial O [ms4][b4][nt256][nn16][c32] f32 (= old CP)
#define O_PS    3116224    // PAM partial S [ms4][b4][nt256][nn16] f32 (inside dead XT, after SCT end)

__device__ __forceinline__ unsigned short f2b(float f){
  __hip_bfloat16 h = __float2bfloat16(f);
  return *(unsigned short*)&h;
}

// ---------------- prep: pack big conv weights to bf16 [tap][cb][co64][cin32] ----------------
__global__ __launch_bounds__(256) void k_prep_wpack(const float* w5a, const float* w5c, float* ws){
  int id = blockIdx.x*256 + threadIdx.x;   // 294912
  int tap = id >> 15;
  int r = id & 32767;
  int cb = r >> 11;
  int r2 = r & 2047;
  int co = r2 >> 5, ci = r2 & 31;
  int cin = cb*32 + ci;
  float v = (co < 32) ? w5a[co*4608 + cin*9 + tap] : w5c[(co-32)*4608 + cin*9 + tap];
  ((unsigned short*)ws)[id] = f2b(v);
}

__global__ __launch_bounds__(256) void k_prep_misc(
  const float* w51, const float* w52,
  const float* s0,const float* b0,const float* m0,const float* v0,
  const float* s1,const float* b1,const float* m1,const float* v1,
  const float* s2,const float* b2,const float* m2,const float* v2,
  const float* s3,const float* b3,const float* m3,const float* v3,
  const float* w8,const float* b8,
  const float* pqw,const float* pqb,const float* pkw,const float* pkb,
  const float* pvw,const float* pvb,const float* pg,const float* cg,
  float* ws)
{
  int id = blockIdx.x*256 + threadIdx.x;
  if (id >= 20076) return;
  if (id < 9216){ int tap=id>>10, co=(id>>5)&31, ci=id&31;
    ((unsigned short*)(ws + O_W51P))[id] = f2b(w51[co*288 + ci*9 + tap]); return; }
  id -= 9216;
  if (id < 9216){ int tap=id>>10, co=(id>>5)&31, ci=id&31;
    ((unsigned short*)(ws + O_W52P))[id] = f2b(w52[co*288 + ci*9 + tap]); return; }
  id -= 9216;
  if (id < 256){
    int conv = id>>6, ab = (id>>5)&1, c = id&31;
    const float *S,*Bb,*M,*V;
    if (conv==0){S=s0;Bb=b0;M=m0;V=v0;} else if (conv==1){S=s1;Bb=b1;M=m1;V=v1;}
    else if (conv==2){S=s2;Bb=b2;M=m2;V=v2;} else {S=s3;Bb=b3;M=m3;V=v3;}
    float A = S[c] * rsqrtf(V[c] + 1e-5f);
    ws[O_BNA + conv*64 + ab*32 + c] = ab ? (Bb[c] - M[c]*A) : A;
    return; }
  id -= 256;
  if (id < 64){ ws[O_W8+id] = w8[id]; return; } id -= 64;
  if (id < 2){ ws[O_W8+64+id] = b8[id]; return; } id -= 2;
  if (id < 128){ ws[O_PQW+id] = pqw[id]; return; } id -= 128;
  if (id < 4){ ws[O_PQW+128+id] = pqb[id]; return; } id -= 4;
  if (id < 128){ ws[O_PKW+id] = pkw[id]; return; } id -= 128;
  if (id < 4){ ws[O_PKW+128+id] = pkb[id]; return; } id -= 4;
  if (id < 1024){ ws[O_PVW+id] = pvw[id]; return; } id -= 1024;
  if (id < 32){ ws[O_PVW+1024+id] = pvb[id]; return; } id -= 32;
  ws[O_GAM+id] = id ? cg[0] : pg[0];
}

// ---------------- zero Xt borders only (ring of 260 px per (b,cb)) ----------------
__global__ __launch_bounds__(256) void k_zero_xtb(float* __restrict__ ws){
  int i = blockIdx.x*256 + threadIdx.x;   // 66560 uint4
  if (i >= 66560) return;
  int part = i & 3; int j = i >> 2;       // 16640
  int rp = j % 260; int bc = j / 260;     // bc = b*16+cb
  int py, px;
  if (rp < 66){ py = 0; px = rp; }
  else if (rp < 132){ py = 65; px = rp - 66; }
  else if (rp < 196){ py = rp - 131; px = 0; }
  else { py = rp - 195; px = 65; }
  size_t off = (((size_t)bc*66 + py)*66 + px)*32 + part*8;
  *(uint4*)((unsigned short*)(ws + O_XT) + off) = make_uint4(0,0,0,0);
}

// ---------------- zero SA_t / SC_t borders ----------------
__global__ __launch_bounds__(256) void k_zero_sascb(float* __restrict__ ws){
  int i = blockIdx.x*256 + threadIdx.x;   // 8320 uint4
  if (i >= 8320) return;
  int part = i & 3; int j = i >> 2;       // 2080
  int arr = j / 1040; int rem = j - arr*1040;
  int b = rem / 260; int rp = rem % 260;
  int py, px;
  if (rp < 66){ py = 0; px = rp; }
  else if (rp < 132){ py = 65; px = rp - 66; }
  else if (rp < 196){ py = rp - 131; px = 0; }
  else { py = rp - 195; px = 65; }
  size_t off = (((size_t)(b*66) + py)*66 + px)*32 + part*8;
  unsigned short* base = (unsigned short*)(ws + O_SAT + arr*278784);
  *(uint4*)(base + off) = make_uint4(0,0,0,0);
}

// ---------------- NHWC+pad bf16 transform: Xt[b][cb16][66][66][32] ----------------
__global__ __launch_bounds__(256) void k_nhwc(const float* __restrict__ x, float* __restrict__ ws){
  int y = blockIdx.x, ct = blockIdx.y, b = blockIdx.z;  // (64, 8, 4)
  __shared__ unsigned short t16[64][65];
  int tid = threadIdx.x;
  int r0 = tid >> 4, c0 = (tid & 15) * 4;
  const float* xb = x + ((size_t)(b*512 + ct*64))*4096 + y*64;
  #pragma unroll
  for (int i = 0; i < 4; ++i){
    int row = r0 + i*16;
    float4 v = *(const float4*)(xb + (size_t)row*4096 + c0);
    t16[row][c0+0] = f2b(v.x);
    t16[row][c0+1] = f2b(v.y);
    t16[row][c0+2] = f2b(v.z);
    t16[row][c0+3] = f2b(v.w);
  }
  __syncthreads();
  int pixl = tid >> 2, q = tid & 3;
  unsigned short vs[16];
  #pragma unroll
  for (int j = 0; j < 16; ++j) vs[j] = t16[q*16 + j][pixl];
  unsigned u[8];
  #pragma unroll
  for (int j = 0; j < 8; ++j) u[j] = (unsigned)vs[2*j] | ((unsigned)vs[2*j+1] << 16);
  unsigned short* xt = (unsigned short*)(ws + O_XT);
  int cbl = ct*2 + (q>>1);
  size_t off = (((size_t)(b*16 + cbl)*66 + (y+1))*66 + (pixl+1))*32 + (q&1)*16;
  *(uint4*)(xt + off)     = make_uint4(u[0],u[1],u[2],u[3]);
  *(uint4*)(xt + off + 8) = make_uint4(u[4],u[5],u[6],u[7]);
}

// ---------------- big convs as implicit GEMM via MFMA (row-slab staging) ----------------
// R4: 4-way cin split (grid 1024 = 4 blocks/CU) + reg-prefetch staging: next slab's
// global loads issue BEFORE the tap loop; their consumer is the ds_write after the
// next barrier, so the compiler cannot sink them — latency hides under MFMA.
__global__ __launch_bounds__(256) void k_conv_mfma(float* __restrict__ ws){
  int mb = blockIdx.x;          // b = mb>>6, y = mb&63
  int ks = blockIdx.y;          // cin quarter (0..3)
  int b = mb >> 6, y = mb & 63;
  __shared__ unsigned short Bs[198*40];   // [dy*66+px][k32 pad40]
  int tid = threadIdx.x;
  int w = tid >> 6, l = tid & 63;
  f32x4 zero = {0.f,0.f,0.f,0.f};
  f32x4 acc[4] = {zero, zero, zero, zero};
  const unsigned short* wp = (const unsigned short*)ws;
  const unsigned short* xt = (const unsigned short*)(ws + O_XT);
  int arow = w*16 + (l & 15);
  int kq = (l >> 4)*8;
  int i0 = tid, i1 = tid + 256, i2 = tid + 512, i3 = tid + 768;  // i3 only if tid<24
  const unsigned short* slab0 = xt + ((size_t)((b*16 + ks*4)*66 + y))*2112;
  uint4 r0 = *(const uint4*)(slab0 + i0*8);
  uint4 r1 = *(const uint4*)(slab0 + i1*8);
  uint4 r2 = *(const uint4*)(slab0 + i2*8);
  uint4 r3 = (tid < 24) ? *(const uint4*)(slab0 + i3*8) : make_uint4(0,0,0,0);
  for (int cb4 = 0; cb4 < 4; ++cb4){
    int cb = ks*4 + cb4;
    __syncthreads();
    *(uint4*)&Bs[(i0>>2)*40 + (i0&3)*8] = r0;
    *(uint4*)&Bs[(i1>>2)*40 + (i1&3)*8] = r1;
    *(uint4*)&Bs[(i2>>2)*40 + (i2&3)*8] = r2;
    if (tid < 24) *(uint4*)&Bs[(i3>>2)*40 + (i3&3)*8] = r3;
    __syncthreads();
    if (cb4 < 3){
      const unsigned short* slab = xt + ((size_t)((b*16 + cb + 1)*66 + y))*2112;
      r0 = *(const uint4*)(slab + i0*8);
      r1 = *(const uint4*)(slab + i1*8);
      r2 = *(const uint4*)(slab + i2*8);
      if (tid < 24) r3 = *(const uint4*)(slab + i3*8);
    }
    #pragma unroll
    for (int tap = 0; tap < 9; ++tap){
      int dy = tap/3, dx = tap - dy*3;
      bf16x8 af = *(const bf16x8*)(wp + (size_t)(tap*16 + cb)*2048 + arow*32 + kq);
      #pragma unroll
      for (int pt = 0; pt < 4; ++pt){
        int pix = pt*16 + (l&15) + dx;
        bf16x8 bv = *(const bf16x8*)&Bs[(dy*66 + pix)*40 + kq];
        acc[pt] = __builtin_amdgcn_mfma_f32_16x16x32_bf16(af, bv, acc[pt], 0, 0, 0);
      }
    }
  }
  float* cp = ws + O_CP + ((size_t)(ks*4 + b))*262144;
  int co0 = w*16 + (l>>4)*4;
  #pragma unroll
  for (int pt = 0; pt < 4; ++pt){
    int pix = y*64 + pt*16 + (l & 15);
    *(f32x4*)&cp[(size_t)pix*64 + co0] = acc[pt];
  }
}

// ---------------- reduce partials (4 cin quarters) + BN + ReLU -> F1T, F2T ----------------
__global__ __launch_bounds__(256) void k_reduce_feat(float* __restrict__ ws){
  int id = blockIdx.x*256 + threadIdx.x;     // 1048576 = (b*4096+pix)*64 + co
  float s = (ws[O_CP + id] + ws[O_CP + 1048576 + id])
          + (ws[O_CP + 2097152 + id] + ws[O_CP + 3145728 + id]);
  int co = id & 63; int rest = id >> 6;      // b*4096+pix
  int conv = co >> 5, c = co & 31;
  float A = ws[O_BNA + conv*64 + c], Bb = ws[O_BNA + conv*64 + 32 + c];
  float val = fmaxf(A*s + Bb, 0.f);
  if (conv == 0) ws[O_F1T + (size_t)rest*32 + c] = val;
  else           ws[O_F2T + (size_t)rest*32 + c] = val;
}

// ---------------- q,k,v 1x1 convs (Q,K f32; V bf16) ----------------
// 256 blocks; thread = (part, b, n): part-th cr of q/k + 8 V channels
__global__ __launch_bounds__(256) void k_qkv(float* __restrict__ ws){
  int id = blockIdx.x*256 + threadIdx.x;  // 65536
  int part = id >> 14;                    // 0..3 (uniform per block)
  int nid = id & 16383;                   // b*4096+n
  int b = nid >> 12, n = nid & 4095;
  __shared__ float wq[32], wk[32], wv[8][32];
  int tid = threadIdx.x;
  if (tid < 32){ wq[tid] = ws[O_PQW + part*32 + tid]; wk[tid] = ws[O_PKW + part*32 + tid]; }
  wv[tid>>5][tid&31] = ws[O_PVW + (part*8 + (tid>>5))*32 + (tid&31)];
  __syncthreads();
  const float* fp = ws + O_F1T + (size_t)nid*32;
  float fv[32];
  #pragma unroll
  for (int j=0;j<8;j++){
    float4 v = *(const float4*)(fp + j*4);
    fv[j*4]=v.x; fv[j*4+1]=v.y; fv[j*4+2]=v.z; fv[j*4+3]=v.w;
  }
  float q = ws[O_PQW+128+part], k = ws[O_PKW+128+part];
  #pragma unroll
  for (int c=0;c<32;c++){ q += wq[c]*fv[c]; k += wk[c]*fv[c]; }
  ws[O_Q + (((b<<2)+part)<<12) + n] = q;
  ws[O_K + (((b<<2)+part)<<12) + n] = k;
  unsigned short* vbp = (unsigned short*)(ws + O_V);
  #pragma unroll
  for (int j2=0;j2<8;j2++){
    int c2 = part*8 + j2;
    float v = ws[O_PVW+1024+c2];
    #pragma unroll
    for (int c=0;c<32;c++) v += wv[j2][c]*fv[c];
    vbp[(((b<<5)+c2)<<12) + n] = f2b(v);
  }
}

// ---------------- PAM flash, m-split x4: QK^T + fixed-shift exp2 softmax + MFMA P@V ----------------
__global__ __launch_bounds__(256, 6) void k_pam_flash(float* __restrict__ ws){
  int nt = blockIdx.x;   // 0..255 n-tile of 16
  int b  = blockIdx.y;   // 0..3
  int ms = blockIdx.z;   // 0..3 m-split
  __shared__ float Ks[2][4][4][32];            // [buf][wave][cr][m32]   4 KB
  __shared__ unsigned short Vs[2][4][1280];    // [buf][wave][c*40+m]   20 KB
  __shared__ float Ss[4][16];
  int tid = threadIdx.x;
  int w = tid >> 6, l = tid & 63;
  int nn = l & 15, g = l >> 4;
  int n = (nt<<4) + nn;
  const float LOG2E = 1.44269504f;
  const float BIAS  = -28.8539008f;   // -20*log2(e); fixed shift, energies O(+-35)
  float q0 = ws[O_Q + (((b<<2)+0)<<12) + n] * LOG2E;
  float q1 = ws[O_Q + (((b<<2)+1)<<12) + n] * LOG2E;
  float q2 = ws[O_Q + (((b<<2)+2)<<12) + n] * LOG2E;
  float q3 = ws[O_Q + (((b<<2)+3)<<12) + n] * LOG2E;
  const unsigned short* vb = (const unsigned short*)(ws + O_V);
  int e0 = l*2, cr_s = e0 >> 5, mm_s = e0 & 31;
  int c_s = l >> 1, mh_s = (l & 1) * 16;
  int mbase = ms*1024 + w*256;        // wave handles m in [mbase, mbase+256), 8 chunks
  const float* ksrc = ws + O_K + (((b<<2)+cr_s)<<12) + mbase + mm_s;
  const unsigned short* vsrc = vb + (((b<<5)+c_s)<<12) + mbase + mh_s;
  int mo = g*8;
  f32x4 zero = {0.f,0.f,0.f,0.f};
  f32x4 acc0 = zero, acc1 = zero, accS = zero;
  union { bf16x8 v; unsigned short u[8]; } ones;
  #pragma unroll
  for (int j=0;j<8;++j) ones.u[j] = 0x3F80;   // bf16 1.0
  float2 kreg = *(const float2*)(ksrc);
  uint4 vr0 = *(const uint4*)(vsrc);
  uint4 vr1 = *(const uint4*)(vsrc + 8);
  *(float2*)&Ks[0][w][cr_s][mm_s] = kreg;
  *(uint4*)&Vs[0][w][c_s*40 + mh_s] = vr0;
  *(uint4*)&Vs[0][w][c_s*40 + mh_s + 8] = vr1;
  for (int ch = 0; ch < 8; ++ch){
    int buf = ch & 1;
    if (ch < 7){
      int m0n = (ch+1)*32;
      kreg = *(const float2*)(ksrc + m0n);
      vr0 = *(const uint4*)(vsrc + m0n);
      vr1 = *(const uint4*)(vsrc + m0n + 8);
    }
    float e[8];
    {
      float4 ka = *(const float4*)&Ks[buf][w][0][mo];
      float4 kb = *(const float4*)&Ks[buf][w][0][mo+4];
      e[0]=fmaf(q0,ka.x,BIAS); e[1]=fmaf(q0,ka.y,BIAS); e[2]=fmaf(q0,ka.z,BIAS); e[3]=fmaf(q0,ka.w,BIAS);
      e[4]=fmaf(q0,kb.x,BIAS); e[5]=fmaf(q0,kb.y,BIAS); e[6]=fmaf(q0,kb.z,BIAS); e[7]=fmaf(q0,kb.w,BIAS);
      ka = *(const float4*)&Ks[buf][w][1][mo]; kb = *(const float4*)&Ks[buf][w][1][mo+4];
      e[0]=fmaf(q1,ka.x,e[0]); e[1]=fmaf(q1,ka.y,e[1]); e[2]=fmaf(q1,ka.z,e[2]); e[3]=fmaf(q1,ka.w,e[3]);
      e[4]=fmaf(q1,kb.x,e[4]); e[5]=fmaf(q1,kb.y,e[5]); e[6]=fmaf(q1,kb.z,e[6]); e[7]=fmaf(q1,kb.w,e[7]);
      ka = *(const float4*)&Ks[buf][w][2][mo]; kb = *(const float4*)&Ks[buf][w][2][mo+4];
      e[0]=fmaf(q2,ka.x,e[0]); e[1]=fmaf(q2,ka.y,e[1]); e[2]=fmaf(q2,ka.z,e[2]); e[3]=fmaf(q2,ka.w,e[3]);
      e[4]=fmaf(q2,kb.x,e[4]); e[5]=fmaf(q2,kb.y,e[5]); e[6]=fmaf(q2,kb.z,e[6]); e[7]=fmaf(q2,kb.w,e[7]);
      ka = *(const float4*)&Ks[buf][w][3][mo]; kb = *(const float4*)&Ks[buf][w][3][mo+4];
      e[0]=fmaf(q3,ka.x,e[0]); e[1]=fmaf(q3,ka.y,e[1]); e[2]=fmaf(q3,ka.z,e[2]); e[3]=fmaf(q3,ka.w,e[3]);
      e[4]=fmaf(q3,kb.x,e[4]); e[5]=fmaf(q3,kb.y,e[5]); e[6]=fmaf(q3,kb.z,e[6]); e[7]=fmaf(q3,kb.w,e[7]);
    }
    union { bf16x8 v; unsigned short u[8]; } pb;
    #pragma unroll
    for (int j=0;j<8;j++) pb.u[j] = f2b(__builtin_amdgcn_exp2f(e[j]));
    bf16x8 a0 = *(const bf16x8*)&Vs[buf][w][nn*40 + mo];
    bf16x8 a1 = *(const bf16x8*)&Vs[buf][w][(16+nn)*40 + mo];
    acc0 = __builtin_amdgcn_mfma_f32_16x16x32_bf16(a0, pb.v, acc0, 0, 0, 0);
    acc1 = __builtin_amdgcn_mfma_f32_16x16x32_bf16(a1, pb.v, acc1, 0, 0, 0);
    accS = __builtin_amdgcn_mfma_f32_16x16x32_bf16(ones.v, pb.v, accS, 0, 0, 0);
    if (ch < 7){
      int nb = buf ^ 1;
      *(float2*)&Ks[nb][w][cr_s][mm_s] = kreg;
      *(uint4*)&Vs[nb][w][c_s*40 + mh_s] = vr0;
      *(uint4*)&Vs[nb][w][c_s*40 + mh_s + 8] = vr1;
    }
  }
  // accS rows identical = sum_m P[n][m] over this wave's m-range
  if (l < 16) Ss[w][l] = accS[0];
  __syncthreads();                       // all waves done reading Vs
  float* Os = (float*)&Vs[0][0][0];      // alias: [4 wave][16 nn][36] f32 (9.2 KB < 20 KB)
  #pragma unroll
  for (int r=0;r<4;r++){
    Os[(w*16+nn)*36 + g*4 + r]      = acc0[r];
    Os[(w*16+nn)*36 + 16 + g*4 + r] = acc1[r];
  }
  __syncthreads();
  float* PO = ws + O_PO + ((size_t)((ms*4+b)*256+nt))*512;
  for (int i = tid; i < 512; i += 256){
    int nn2 = i >> 5, c = i & 31;
    PO[i] = Os[nn2*36 + c] + Os[(16+nn2)*36 + c] + Os[(32+nn2)*36 + c] + Os[(48+nn2)*36 + c];
  }
  if (tid < 16)
    ws[O_PS + ((ms*4+b)*256+nt)*16 + tid] = Ss[0][tid]+Ss[1][tid]+Ss[2][tid]+Ss[3][tid];
}

// ---------------- PAM finalize: combine 4 m-split partials, divide, residual -> SA_t ----------------
__global__ __launch_bounds__(256) void k_pam_fin(float* __restrict__ ws){
  int id = blockIdx.x*256 + threadIdx.x;   // 524288 = (b*4096+n)*32 + c
  int c = id & 31;
  int n = (id >> 5) & 4095;
  int b = id >> 17;
  int nt = n >> 4, nn = n & 15;
  int pbase = ((b*256+nt)*512) + nn*32 + c;
  int sbase = (b*256+nt)*16 + nn;
  float O = ws[O_PO + pbase] + ws[O_PO + 524288 + pbase]
          + ws[O_PO + 1048576 + pbase] + ws[O_PO + 1572864 + pbase];
  float S = ws[O_PS + sbase] + ws[O_PS + 16384 + sbase]
          + ws[O_PS + 32768 + sbase] + ws[O_PS + 49152 + sbase];
  float sa = ws[O_GAM]*(O/S) + ws[O_F1T + id];
  int y = n >> 6, xx = n & 63;
  ((unsigned short*)(ws + O_SAT))[(((size_t)((b*66 + y+1)*66 + xx+1))<<5) + c] = f2b(sa);
}

// ---------------- CAM energy: outer-product partials (F2T read ONCE) ----------------
// grid 256 = (b4 x chunk64 of 64 n); thread (c, d0/4) accumulates 4 Gram entries.
__global__ __launch_bounds__(256) void k_cam_energy(float* __restrict__ ws){
  int blk = blockIdx.x; int b = blk >> 6, ch = blk & 63;
  __shared__ float Fs[64*32];   // 8 KB
  int tid = threadIdx.x;
  const float* f = ws + O_F2T + ((size_t)b<<17) + (size_t)ch*2048;
  for (int i = tid; i < 512; i += 256)
    *(float4*)&Fs[i*4] = *(const float4*)(f + i*4);
  __syncthreads();
  int c = tid >> 3, d0 = (tid & 7) * 4;
  float a0=0.f, a1=0.f, a2=0.f, a3=0.f;
  #pragma unroll 8
  for (int n = 0; n < 64; ++n){
    float fc = Fs[n*32 + c];
    float4 fd = *(const float4*)&Fs[n*32 + d0];
    a0 = fmaf(fc, fd.x, a0); a1 = fmaf(fc, fd.y, a1);
    a2 = fmaf(fc, fd.z, a2); a3 = fmaf(fc, fd.w, a3);
  }
  float* pe = ws + O_PE + ((size_t)(b*64 + ch))*1024;
  *(float4*)&pe[c*32 + d0] = make_float4(a0, a1, a2, a3);
}

// ---------------- CAM energy reduce: ENE[b][c][d] = sum over 64 chunk partials ----------------
__global__ __launch_bounds__(256) void k_cam_red(float* __restrict__ ws){
  int id = blockIdx.x*256 + threadIdx.x;   // 4096 = b*1024 + i
  int b = id >> 10, i = id & 1023;
  const float* pe = ws + O_PE + ((size_t)b<<16) + i;
  float s = 0.f;
  #pragma unroll 8
  for (int chk = 0; chk < 64; ++chk) s += pe[chk*1024];
  ws[O_ENE + id] = s;
}

// ---------------- CAM att (in-block) + out -> SC_t ----------------
// 128 blocks; thread = (half, 128 n): 16 output channels each
__global__ __launch_bounds__(256) void k_cam_out(float* __restrict__ ws){
  int blk = blockIdx.x;            // 128
  int b = blk >> 5;
  int chunk = blk & 31;
  int tid = threadIdx.x;
  int half = tid >> 7;             // 0/1
  int nl = tid & 127;
  int n = (chunk << 7) + nl;
  __shared__ float att[32][33];
  if (tid < 32){
    int c = tid;
    const float* e = ws + O_ENE + (b<<10) + (c<<5);
    float M = -1e30f, mn = 1e30f;
    #pragma unroll
    for (int d=0;d<32;d++){ M = fmaxf(M, e[d]); mn = fminf(mn, e[d]); }
    float mx2 = M - mn;
    float s = 0.f, ex[32];
    #pragma unroll
    for (int d=0;d<32;d++){ ex[d] = __expf((M - e[d]) - mx2); s += ex[d]; }
    float inv = 1.f/s;
    #pragma unroll
    for (int d=0;d<32;d++) att[c][d] = ex[d]*inv;
  }
  __syncthreads();
  const float* fp = ws + O_F2T + (((size_t)b<<12) + n)*32;
  float fv[32];
  #pragma unroll
  for (int j=0;j<8;j++){
    float4 v = *(const float4*)(fp + j*4);
    fv[j*4]=v.x; fv[j*4+1]=v.y; fv[j*4+2]=v.z; fv[j*4+3]=v.w;
  }
  float g = ws[O_GAM+1];
  int c0 = half*16;
  unsigned u[8];
  #pragma unroll
  for (int cp=0; cp<8; ++cp){
    int ca = c0 + 2*cp, cb = ca + 1;
    float o0 = 0.f, o1 = 0.f;
    #pragma unroll
    for (int d=0;d<32;d++){ o0 += att[ca][d]*fv[d]; o1 += att[cb][d]*fv[d]; }
    float r0 = g*o0 + fv[ca], r1 = g*o1 + fv[cb];
    u[cp] = (unsigned)f2b(r0) | ((unsigned)f2b(r1) << 16);
  }
  int y = n >> 6, xcol = n & 63;
  unsigned short* sct = (unsigned short*)(ws + O_SCT);
  size_t base = ((size_t)((b*66 + y+1)*66 + xcol+1))*32 + c0;
  *(uint4*)(sct + base)     = make_uint4(u[0],u[1],u[2],u[3]);
  *(uint4*)(sct + base + 8) = make_uint4(u[4],u[5],u[6],u[7]);
}

// ---------------- fused conv51+conv52 (MFMA) + BN/ReLU + sum + 1x1 conv8 + ReLU ----------------
__global__ __launch_bounds__(256) void k_final_mfma(float* __restrict__ ws, float* __restrict__ out){
  int y = blockIdx.x, b = blockIdx.y;          // (64, 4)
  __shared__ unsigned short Bs[2*3*66*40];     // [conv][dy][pix66][k32 pad40]
  __shared__ float ep[2][2][2][16];            // [wavepair][pt][o][pix16]
  int tid = threadIdx.x;
  int w = tid >> 6, l = tid & 63;
  int g = l >> 4, col = l & 15;
  const unsigned short* sat = (const unsigned short*)(ws + O_SAT);
  const unsigned short* sct = (const unsigned short*)(ws + O_SCT);
  for (int i = tid; i < 1584; i += 256){
    int row = i >> 2, part = i & 3;
    int conv = row / 198; int rr = row - conv*198;
    int dy = rr / 66; int pix = rr - dy*66;
    const unsigned short* src = (conv ? sct : sat) + ((size_t)((b*66 + y + dy)*66 + pix))*32 + part*8;
    *(uint4*)&Bs[(size_t)row*40 + part*8] = *(const uint4*)src;
  }
  __syncthreads();
  int cohalf = w & 1, ptbase = (w >> 1) * 2;
  const unsigned short* wp[2] = { (const unsigned short*)(ws + O_W51P), (const unsigned short*)(ws + O_W52P) };
  f32x4 zero = {0.f,0.f,0.f,0.f};
  f32x4 acc[2][2] = {{zero,zero},{zero,zero}};
  for (int dy = 0; dy < 3; ++dy){
    for (int dx = 0; dx < 3; ++dx){
      int tap = dy*3 + dx;
      #pragma unroll
      for (int conv = 0; conv < 2; ++conv){
        bf16x8 af = *(const bf16x8*)(wp[conv] + tap*1024 + (cohalf*16 + col)*32 + g*8);
        #pragma unroll
        for (int pt = 0; pt < 2; ++pt){
          int pix = (ptbase + pt)*16 + col + dx;
          bf16x8 bv = *(const bf16x8*)&Bs[(size_t)((conv*3 + dy)*66 + pix)*40 + g*8];
          acc[conv][pt] = __builtin_amdgcn_mfma_f32_16x16x32_bf16(af, bv, acc[conv][pt], 0, 0, 0);
        }
      }
    }
  }
  float p0[2], p1[2];
  #pragma unroll
  for (int pt = 0; pt < 2; ++pt){
    float s0 = 0.f, s1 = 0.f;
    #pragma unroll
    for (int r = 0; r < 4; ++r){
      int co = cohalf*16 + g*4 + r;
      float A1 = ws[O_BNA + 2*64 + co], B1 = ws[O_BNA + 2*64 + 32 + co];
      float A2 = ws[O_BNA + 3*64 + co], B2 = ws[O_BNA + 3*64 + 32 + co];
      float fs = fmaxf(A1*acc[0][pt][r] + B1, 0.f) + fmaxf(A2*acc[1][pt][r] + B2, 0.f);
      s0 += ws[O_W8 + co]*fs;
      s1 += ws[O_W8 + 32 + co]*fs;
    }
    s0 += __shfl_xor(s0, 16); s0 += __shfl_xor(s0, 32);
    s1 += __shfl_xor(s1, 16); s1 += __shfl_xor(s1, 32);
    p0[pt] = s0; p1[pt] = s1;
  }
  if (cohalf == 0 && l < 16){
    #pragma unroll
    for (int pt = 0; pt < 2; ++pt){ ep[w>>1][pt][0][l] = p0[pt]; ep[w>>1][pt][1][l] = p1[pt]; }
  }
  __syncthreads();
  if (cohalf == 1 && l < 16){
    float b80 = ws[O_W8 + 64], b81 = ws[O_W8 + 65];
    #pragma unroll
    for (int pt = 0; pt < 2; ++pt){
      int pix = y*64 + (w>>1)*32 + pt*16 + l;
      float o0 = p0[pt] + ep[w>>1][pt][0][l] + b80;
      float o1 = p1[pt] + ep[w>>1][pt][1][l] + b81;
      out[((b*2+0)<<12) + pix] = fmaxf(o0, 0.f);
      out[((b*2+1)<<12) + pix] = fmaxf(o1, 0.f);
    }
  }
}

extern "C" void kernel_launch(void* const* d_in, const int* in_sizes, int n_in,
                              void* d_out, int out_size, void* d_ws, size_t ws_size,
                              hipStream_t stream) {
  const float* x    = (const float*)d_in[0];
  const float* w5a  = (const float*)d_in[1];
  const float* w5c  = (const float*)d_in[18];
  const float* w51  = (const float*)d_in[13];
  const float* w52  = (const float*)d_in[24];
  float* ws = (float*)d_ws;
  float* out = (float*)d_out;

  k_prep_wpack<<<1152, 256, 0, stream>>>(w5a, w5c, ws);
  k_prep_misc<<<79, 256, 0, stream>>>(
      w51, w52,
      (const float*)d_in[2],(const float*)d_in[3],(const float*)d_in[4],(const float*)d_in[5],
      (const float*)d_in[19],(const float*)d_in[20],(const float*)d_in[21],(const float*)d_in[22],
      (const float*)d_in[14],(const float*)d_in[15],(const float*)d_in[16],(const float*)d_in[17],
      (const float*)d_in[25],(const float*)d_in[26],(const float*)d_in[27],(const float*)d_in[28],
      (const float*)d_in[29],(const float*)d_in[30],
      (const float*)d_in[6],(const float*)d_in[7],(const float*)d_in[8],(const float*)d_in[9],
      (const float*)d_in[10],(const float*)d_in[11],(const float*)d_in[12],(const float*)d_in[23],
      ws);
  k_zero_xtb<<<260, 256, 0, stream>>>(ws);
  k_nhwc<<<dim3(64,8,4), 256, 0, stream>>>(x, ws);
  k_conv_mfma<<<dim3(256,4), 256, 0, stream>>>(ws);
  k_reduce_feat<<<4096, 256, 0, stream>>>(ws);
  k_zero_sascb<<<33, 256, 0, stream>>>(ws);
  k_qkv<<<256, 256, 0, stream>>>(ws);
  k_pam_flash<<<dim3(256,4,4), 256, 0, stream>>>(ws);
  k_pam_fin<<<2048, 256, 0, stream>>>(ws);
  k_cam_energy<<<256, 256, 0, stream>>>(ws);
  k_cam_red<<<16, 256, 0, stream>>>(ws);
  k_cam_out<<<128, 256, 0, stream>>>(ws);
  k_final_mfma<<<dim3(64,4), 256, 0, stream>>>(ws, out);
}

// Round 6
// 96.725 us; speedup vs baseline: 1.7610x; 1.2105x over previous
//
#include <hip/hip_runtime.h>
#include <hip/hip_bf16.h>

// all I/O is float32 (reference is pure jnp.float32)

typedef __attribute__((ext_vector_type(8))) short bf16x8;
typedef __attribute__((ext_vector_type(4))) float f32x4;

// ---- ws layout (f32 element offsets) ----
#define O_WPK   0          // Wpack [tap9][cb16][co64][cin32] bf16 (big convs)
#define O_W51P  147456     // [tap9][co32][ci32] bf16
#define O_W52P  152064
#define O_BNA   156672     // [conv{5a,5c,51,52}][{A,B}][32]
#define O_W8    156928     // w8[2][32], b8 at +64
#define O_PQW   157000     // [4][32], bias at +128
#define O_PKW   157132
#define O_PVW   157264     // [32][32], bias at +1024
#define O_GAM   158320     // p_gamma, c_gamma
#define O_Q     158400     // [b4][cr4][4096] f32
#define O_K     223936     // [b4][cr4][4096] f32
#define O_ENE   453312     // [4][32][32]
#define O_PE    457408     // CAM energy partials [b4][ch64][32][32] f32 (ends 719552)
#define O_F1T   985792     // [b][4096][32] f32 NHWC
#define O_F2T   1510080    // [b][4096][32] f32 NHWC
#define O_V     2034368    // [b][32][4096] bf16
#define O_SAT   2558656    // [b][66][66][32] bf16 padded  (INSIDE XT overlay!)
#define O_SCT   2837440
// conv-phase overlays (Xt dead after k_conv_mfma):
#define O_XT    461504     // Xt[b4][cb16][66][66][32] bf16 (ends 4922048)
#define O_CP    4922048    // conv partials f32 [ks4][b4][4096pix][64co] (ends 9116352)
// PAM-phase overlays (CP dead after k_reduce_feat; XT dead after k_conv_mfma):
#define O_PO    4922048    // PAM partial O [ms4][b4][n4096][c32] f32 (= old CP)
#define O_PS    3116224    // PAM partial S [ms4][b4][n4096] f32 (inside dead XT, after SCT end)

__device__ __forceinline__ unsigned short f2b(float f){
  __hip_bfloat16 h = __float2bfloat16(f);
  return *(unsigned short*)&h;
}

// ---------------- fused prep: wpack + misc + zero XT borders ----------------
// NOTE: SAT/SCT halo zeroing must NOT happen here — SAT/SCT live inside the XT
// overlay, and k_nhwc (which writes all XT interior) would clobber the zeros.
// It is done in k_reduce_feat (after conv, XT dead) instead.  [R5 bug fix]
__global__ __launch_bounds__(256) void k_prep_all(
  const float* w5a, const float* w5c,
  const float* w51, const float* w52,
  const float* s0,const float* b0,const float* m0,const float* v0,
  const float* s1,const float* b1,const float* m1,const float* v1,
  const float* s2,const float* b2,const float* m2,const float* v2,
  const float* s3,const float* b3,const float* m3,const float* v3,
  const float* w8,const float* b8,
  const float* pqw,const float* pqb,const float* pkw,const float* pkb,
  const float* pvw,const float* pvb,const float* pg,const float* cg,
  float* ws)
{
  int bx = blockIdx.x;
  int tid = threadIdx.x;
  if (bx < 1152){
    // ---- pack big conv weights to bf16 [tap][cb][co64][cin32]
    int id = bx*256 + tid;   // 294912
    int tap = id >> 15;
    int r = id & 32767;
    int cb = r >> 11;
    int r2 = r & 2047;
    int co = r2 >> 5, ci = r2 & 31;
    int cin = cb*32 + ci;
    float v = (co < 32) ? w5a[co*4608 + cin*9 + tap] : w5c[(co-32)*4608 + cin*9 + tap];
    ((unsigned short*)ws)[id] = f2b(v);
    return;
  }
  if (bx < 1231){
    // ---- misc params
    int id = (bx-1152)*256 + tid;
    if (id >= 20076) return;
    if (id < 9216){ int tap=id>>10, co=(id>>5)&31, ci=id&31;
      ((unsigned short*)(ws + O_W51P))[id] = f2b(w51[co*288 + ci*9 + tap]); return; }
    id -= 9216;
    if (id < 9216){ int tap=id>>10, co=(id>>5)&31, ci=id&31;
      ((unsigned short*)(ws + O_W52P))[id] = f2b(w52[co*288 + ci*9 + tap]); return; }
    id -= 9216;
    if (id < 256){
      int conv = id>>6, ab = (id>>5)&1, c = id&31;
      const float *S,*Bb,*M,*V;
      if (conv==0){S=s0;Bb=b0;M=m0;V=v0;} else if (conv==1){S=s1;Bb=b1;M=m1;V=v1;}
      else if (conv==2){S=s2;Bb=b2;M=m2;V=v2;} else {S=s3;Bb=b3;M=m3;V=v3;}
      float A = S[c] * rsqrtf(V[c] + 1e-5f);
      ws[O_BNA + conv*64 + ab*32 + c] = ab ? (Bb[c] - M[c]*A) : A;
      return; }
    id -= 256;
    if (id < 64){ ws[O_W8+id] = w8[id]; return; } id -= 64;
    if (id < 2){ ws[O_W8+64+id] = b8[id]; return; } id -= 2;
    if (id < 128){ ws[O_PQW+id] = pqw[id]; return; } id -= 128;
    if (id < 4){ ws[O_PQW+128+id] = pqb[id]; return; } id -= 4;
    if (id < 128){ ws[O_PKW+id] = pkw[id]; return; } id -= 128;
    if (id < 4){ ws[O_PKW+128+id] = pkb[id]; return; } id -= 4;
    if (id < 1024){ ws[O_PVW+id] = pvw[id]; return; } id -= 1024;
    if (id < 32){ ws[O_PVW+1024+id] = pvb[id]; return; } id -= 32;
    ws[O_GAM+id] = id ? cg[0] : pg[0];
    return;
  }
  {
    // ---- zero Xt borders (ring of 260 px per (b,cb)) — safe: nhwc writes interior only
    int i = (bx-1231)*256 + tid;   // 66560 uint4
    if (i >= 66560) return;
    int part = i & 3; int j = i >> 2;
    int rp = j % 260; int bc = j / 260;
    int py, px;
    if (rp < 66){ py = 0; px = rp; }
    else if (rp < 132){ py = 65; px = rp - 66; }
    else if (rp < 196){ py = rp - 131; px = 0; }
    else { py = rp - 195; px = 65; }
    size_t off = (((size_t)bc*66 + py)*66 + px)*32 + part*8;
    *(uint4*)((unsigned short*)(ws + O_XT) + off) = make_uint4(0,0,0,0);
  }
}

// ---------------- NHWC+pad bf16 transform: Xt[b][cb16][66][66][32] ----------------
__global__ __launch_bounds__(256) void k_nhwc(const float* __restrict__ x, float* __restrict__ ws){
  int y = blockIdx.x, ct = blockIdx.y, b = blockIdx.z;  // (64, 8, 4)
  __shared__ unsigned short t16[64][65];
  int tid = threadIdx.x;
  int r0 = tid >> 4, c0 = (tid & 15) * 4;
  const float* xb = x + ((size_t)(b*512 + ct*64))*4096 + y*64;
  #pragma unroll
  for (int i = 0; i < 4; ++i){
    int row = r0 + i*16;
    float4 v = *(const float4*)(xb + (size_t)row*4096 + c0);
    t16[row][c0+0] = f2b(v.x);
    t16[row][c0+1] = f2b(v.y);
    t16[row][c0+2] = f2b(v.z);
    t16[row][c0+3] = f2b(v.w);
  }
  __syncthreads();
  int pixl = tid >> 2, q = tid & 3;
  unsigned short vs[16];
  #pragma unroll
  for (int j = 0; j < 16; ++j) vs[j] = t16[q*16 + j][pixl];
  unsigned u[8];
  #pragma unroll
  for (int j = 0; j < 8; ++j) u[j] = (unsigned)vs[2*j] | ((unsigned)vs[2*j+1] << 16);
  unsigned short* xt = (unsigned short*)(ws + O_XT);
  int cbl = ct*2 + (q>>1);
  size_t off = (((size_t)(b*16 + cbl)*66 + (y+1))*66 + (pixl+1))*32 + (q&1)*16;
  *(uint4*)(xt + off)     = make_uint4(u[0],u[1],u[2],u[3]);
  *(uint4*)(xt + off + 8) = make_uint4(u[4],u[5],u[6],u[7]);
}

// ---------------- big convs as implicit GEMM via MFMA (row-slab staging, reg prefetch) ----------------
__global__ __launch_bounds__(256) void k_conv_mfma(float* __restrict__ ws){
  int mb = blockIdx.x;          // b = mb>>6, y = mb&63
  int ks = blockIdx.y;          // cin quarter (0..3)
  int b = mb >> 6, y = mb & 63;
  __shared__ unsigned short Bs[198*40];   // [dy*66+px][k32 pad40]
  int tid = threadIdx.x;
  int w = tid >> 6, l = tid & 63;
  f32x4 zero = {0.f,0.f,0.f,0.f};
  f32x4 acc[4] = {zero, zero, zero, zero};
  const unsigned short* wp = (const unsigned short*)ws;
  const unsigned short* xt = (const unsigned short*)(ws + O_XT);
  int arow = w*16 + (l & 15);
  int kq = (l >> 4)*8;
  int i0 = tid, i1 = tid + 256, i2 = tid + 512, i3 = tid + 768;  // i3 only if tid<24
  const unsigned short* slab0 = xt + ((size_t)((b*16 + ks*4)*66 + y))*2112;
  uint4 r0 = *(const uint4*)(slab0 + i0*8);
  uint4 r1 = *(const uint4*)(slab0 + i1*8);
  uint4 r2 = *(const uint4*)(slab0 + i2*8);
  uint4 r3 = (tid < 24) ? *(const uint4*)(slab0 + i3*8) : make_uint4(0,0,0,0);
  for (int cb4 = 0; cb4 < 4; ++cb4){
    int cb = ks*4 + cb4;
    __syncthreads();
    *(uint4*)&Bs[(i0>>2)*40 + (i0&3)*8] = r0;
    *(uint4*)&Bs[(i1>>2)*40 + (i1&3)*8] = r1;
    *(uint4*)&Bs[(i2>>2)*40 + (i2&3)*8] = r2;
    if (tid < 24) *(uint4*)&Bs[(i3>>2)*40 + (i3&3)*8] = r3;
    __syncthreads();
    if (cb4 < 3){
      const unsigned short* slab = xt + ((size_t)((b*16 + cb + 1)*66 + y))*2112;
      r0 = *(const uint4*)(slab + i0*8);
      r1 = *(const uint4*)(slab + i1*8);
      r2 = *(const uint4*)(slab + i2*8);
      if (tid < 24) r3 = *(const uint4*)(slab + i3*8);
    }
    #pragma unroll
    for (int tap = 0; tap < 9; ++tap){
      int dy = tap/3, dx = tap - dy*3;
      bf16x8 af = *(const bf16x8*)(wp + (size_t)(tap*16 + cb)*2048 + arow*32 + kq);
      #pragma unroll
      for (int pt = 0; pt < 4; ++pt){
        int pix = pt*16 + (l&15) + dx;
        bf16x8 bv = *(const bf16x8*)&Bs[(dy*66 + pix)*40 + kq];
        acc[pt] = __builtin_amdgcn_mfma_f32_16x16x32_bf16(af, bv, acc[pt], 0, 0, 0);
      }
    }
  }
  float* cp = ws + O_CP + ((size_t)(ks*4 + b))*262144;
  int co0 = w*16 + (l>>4)*4;
  #pragma unroll
  for (int pt = 0; pt < 4; ++pt){
    int pix = y*64 + pt*16 + (l & 15);
    *(f32x4*)&cp[(size_t)pix*64 + co0] = acc[pt];
  }
}

// ---------------- reduce partials + BN + ReLU -> F1T, F2T  (+ SA/SC halo zero) ----------------
// Runs after conv: XT is dead, so zeroing the SAT/SCT borders here survives until final.
__global__ __launch_bounds__(256) void k_reduce_feat(float* __restrict__ ws){
  int bx = blockIdx.x;
  if (bx < 4096){
    int id = bx*256 + threadIdx.x;     // 1048576 = (b*4096+pix)*64 + co
    float s = (ws[O_CP + id] + ws[O_CP + 1048576 + id])
            + (ws[O_CP + 2097152 + id] + ws[O_CP + 3145728 + id]);
    int co = id & 63; int rest = id >> 6;      // b*4096+pix
    int conv = co >> 5, c = co & 31;
    float A = ws[O_BNA + conv*64 + c], Bb = ws[O_BNA + conv*64 + 32 + c];
    float val = fmaxf(A*s + Bb, 0.f);
    if (conv == 0) ws[O_F1T + (size_t)rest*32 + c] = val;
    else           ws[O_F2T + (size_t)rest*32 + c] = val;
    return;
  }
  {
    // ---- zero SA_t / SC_t borders
    int i = (bx-4096)*256 + threadIdx.x;   // 8320 uint4
    if (i >= 8320) return;
    int part = i & 3; int j = i >> 2;
    int arr = j / 1040; int rem = j - arr*1040;
    int b = rem / 260; int rp = rem % 260;
    int py, px;
    if (rp < 66){ py = 0; px = rp; }
    else if (rp < 132){ py = 65; px = rp - 66; }
    else if (rp < 196){ py = rp - 131; px = 0; }
    else { py = rp - 195; px = 65; }
    size_t off = (((size_t)(b*66) + py)*66 + px)*32 + part*8;
    unsigned short* base = (unsigned short*)(ws + O_SAT + arr*278784);
    *(uint4*)(base + off) = make_uint4(0,0,0,0);
  }
}

// ---------------- fused: q,k,v 1x1 convs  +  CAM energy partials ----------------
// bx < 256: qkv (thread = (part, b, n)); bx >= 256: CAM outer-product partials.
__global__ __launch_bounds__(256) void k_qkv_came(float* __restrict__ ws){
  int bx = blockIdx.x;
  int tid = threadIdx.x;
  __shared__ float wq[32], wk[32], wv[8][32];
  __shared__ float Fs[64*32];
  if (bx < 256){
    int id = bx*256 + tid;  // 65536
    int part = id >> 14;                    // 0..3 (uniform per block)
    int nid = id & 16383;                   // b*4096+n
    int b = nid >> 12, n = nid & 4095;
    if (tid < 32){ wq[tid] = ws[O_PQW + part*32 + tid]; wk[tid] = ws[O_PKW + part*32 + tid]; }
    wv[tid>>5][tid&31] = ws[O_PVW + (part*8 + (tid>>5))*32 + (tid&31)];
    __syncthreads();
    const float* fp = ws + O_F1T + (size_t)nid*32;
    float fv[32];
    #pragma unroll
    for (int j=0;j<8;j++){
      float4 v = *(const float4*)(fp + j*4);
      fv[j*4]=v.x; fv[j*4+1]=v.y; fv[j*4+2]=v.z; fv[j*4+3]=v.w;
    }
    float q = ws[O_PQW+128+part], k = ws[O_PKW+128+part];
    #pragma unroll
    for (int c=0;c<32;c++){ q += wq[c]*fv[c]; k += wk[c]*fv[c]; }
    ws[O_Q + (((b<<2)+part)<<12) + n] = q;
    ws[O_K + (((b<<2)+part)<<12) + n] = k;
    unsigned short* vbp = (unsigned short*)(ws + O_V);
    #pragma unroll
    for (int j2=0;j2<8;j2++){
      int c2 = part*8 + j2;
      float v = ws[O_PVW+1024+c2];
      #pragma unroll
      for (int c=0;c<32;c++) v += wv[j2][c]*fv[c];
      vbp[(((b<<5)+c2)<<12) + n] = f2b(v);
    }
    return;
  }
  {
    int blk = bx - 256; int b = blk >> 6, ch = blk & 63;
    const float* f = ws + O_F2T + ((size_t)b<<17) + (size_t)ch*2048;
    for (int i = tid; i < 512; i += 256)
      *(float4*)&Fs[i*4] = *(const float4*)(f + i*4);
    __syncthreads();
    int c = tid >> 3, d0 = (tid & 7) * 4;
    float a0=0.f, a1=0.f, a2=0.f, a3=0.f;
    #pragma unroll 8
    for (int n = 0; n < 64; ++n){
      float fc = Fs[n*32 + c];
      float4 fd = *(const float4*)&Fs[n*32 + d0];
      a0 = fmaf(fc, fd.x, a0); a1 = fmaf(fc, fd.y, a1);
      a2 = fmaf(fc, fd.z, a2); a3 = fmaf(fc, fd.w, a3);
    }
    float* pe = ws + O_PE + ((size_t)(b*64 + ch))*1024;
    *(float4*)&pe[c*32 + d0] = make_float4(a0, a1, a2, a3);
  }
}

// ---------------- PAM flash, 32-n tiles, m-split x4, V direct-to-register ----------------
__global__ __launch_bounds__(256, 6) void k_pam_flash(float* __restrict__ ws){
  int nt = blockIdx.x;   // 0..127 n-tile of 32
  int b  = blockIdx.y;   // 0..3
  int ms = blockIdx.z;   // 0..3 m-split
  __shared__ float Ks[2][4][4][32];    // [buf][wave][cr][m32]  4 KB
  __shared__ float Ss[4][32];
  __shared__ float Os[4][32][36];      // 18 KB
  int tid = threadIdx.x;
  int w = tid >> 6, l = tid & 63;
  int nn = l & 15, g = l >> 4;
  int n0 = (nt<<5) + nn;
  const float LOG2E = 1.44269504f;
  const float BIAS  = -28.8539008f;   // -20*log2(e); fixed shift, energies O(+-35)
  float q0[4], q1[4];
  #pragma unroll
  for (int cr=0;cr<4;++cr){
    q0[cr] = ws[O_Q + (((b<<2)+cr)<<12) + n0] * LOG2E;
    q1[cr] = ws[O_Q + (((b<<2)+cr)<<12) + n0 + 16] * LOG2E;
  }
  int e0i = l*2, cr_s = e0i >> 5, mm_s = e0i & 31;
  int mbase = ms*1024 + w*256;        // wave owns m in [mbase, mbase+256), 8 chunks
  const float* ksrc = ws + O_K + (((b<<2)+cr_s)<<12) + mbase + mm_s;
  const unsigned short* vb = (const unsigned short*)(ws + O_V);
  int mo = g*8;
  const unsigned short* vp0 = vb + (((b<<5) + nn)<<12) + mbase + mo;
  const unsigned short* vp1 = vb + (((b<<5) + 16 + nn)<<12) + mbase + mo;
  f32x4 zero = {0.f,0.f,0.f,0.f};
  f32x4 acc00 = zero, acc01 = zero, acc10 = zero, acc11 = zero;
  float lsum0 = 0.f, lsum1 = 0.f;
  bf16x8 a0A = *(const bf16x8*)(vp0);
  bf16x8 a1A = *(const bf16x8*)(vp1);
  float2 kreg = *(const float2*)(ksrc);
  *(float2*)&Ks[0][w][cr_s][mm_s] = kreg;
  bf16x8 a0B, a1B;
  for (int ch = 0; ch < 8; ++ch){
    int buf = ch & 1;
    if (ch < 7){
      int mn = (ch+1)*32;
      a0B = *(const bf16x8*)(vp0 + mn);
      a1B = *(const bf16x8*)(vp1 + mn);
      kreg = *(const float2*)(ksrc + mn);
    }
    float e0[8], e1[8];
    {
      float4 ka, kb;
      ka = *(const float4*)&Ks[buf][w][0][mo];
      kb = *(const float4*)&Ks[buf][w][0][mo+4];
      e0[0]=fmaf(q0[0],ka.x,BIAS); e0[1]=fmaf(q0[0],ka.y,BIAS); e0[2]=fmaf(q0[0],ka.z,BIAS); e0[3]=fmaf(q0[0],ka.w,BIAS);
      e0[4]=fmaf(q0[0],kb.x,BIAS); e0[5]=fmaf(q0[0],kb.y,BIAS); e0[6]=fmaf(q0[0],kb.z,BIAS); e0[7]=fmaf(q0[0],kb.w,BIAS);
      e1[0]=fmaf(q1[0],ka.x,BIAS); e1[1]=fmaf(q1[0],ka.y,BIAS); e1[2]=fmaf(q1[0],ka.z,BIAS); e1[3]=fmaf(q1[0],ka.w,BIAS);
      e1[4]=fmaf(q1[0],kb.x,BIAS); e1[5]=fmaf(q1[0],kb.y,BIAS); e1[6]=fmaf(q1[0],kb.z,BIAS); e1[7]=fmaf(q1[0],kb.w,BIAS);
#define KACC(CR) \
      ka = *(const float4*)&Ks[buf][w][CR][mo]; \
      kb = *(const float4*)&Ks[buf][w][CR][mo+4]; \
      e0[0]=fmaf(q0[CR],ka.x,e0[0]); e0[1]=fmaf(q0[CR],ka.y,e0[1]); e0[2]=fmaf(q0[CR],ka.z,e0[2]); e0[3]=fmaf(q0[CR],ka.w,e0[3]); \
      e0[4]=fmaf(q0[CR],kb.x,e0[4]); e0[5]=fmaf(q0[CR],kb.y,e0[5]); e0[6]=fmaf(q0[CR],kb.z,e0[6]); e0[7]=fmaf(q0[CR],kb.w,e0[7]); \
      e1[0]=fmaf(q1[CR],ka.x,e1[0]); e1[1]=fmaf(q1[CR],ka.y,e1[1]); e1[2]=fmaf(q1[CR],ka.z,e1[2]); e1[3]=fmaf(q1[CR],ka.w,e1[3]); \
      e1[4]=fmaf(q1[CR],kb.x,e1[4]); e1[5]=fmaf(q1[CR],kb.y,e1[5]); e1[6]=fmaf(q1[CR],kb.z,e1[6]); e1[7]=fmaf(q1[CR],kb.w,e1[7]);
      KACC(1)
      KACC(2)
      KACC(3)
#undef KACC
    }
    union { bf16x8 v; unsigned short u[8]; } pb0, pb1;
    #pragma unroll
    for (int j=0;j<8;j++){ float p = __builtin_amdgcn_exp2f(e0[j]); lsum0 += p; pb0.u[j] = f2b(p); }
    #pragma unroll
    for (int j=0;j<8;j++){ float p = __builtin_amdgcn_exp2f(e1[j]); lsum1 += p; pb1.u[j] = f2b(p); }
    acc00 = __builtin_amdgcn_mfma_f32_16x16x32_bf16(a0A, pb0.v, acc00, 0, 0, 0);
    acc01 = __builtin_amdgcn_mfma_f32_16x16x32_bf16(a1A, pb0.v, acc01, 0, 0, 0);
    acc10 = __builtin_amdgcn_mfma_f32_16x16x32_bf16(a0A, pb1.v, acc10, 0, 0, 0);
    acc11 = __builtin_amdgcn_mfma_f32_16x16x32_bf16(a1A, pb1.v, acc11, 0, 0, 0);
    if (ch < 7){
      int nb = buf ^ 1;
      *(float2*)&Ks[nb][w][cr_s][mm_s] = kreg;
      a0A = a0B; a1A = a1B;
    }
  }
  lsum0 += __shfl_xor(lsum0, 16); lsum0 += __shfl_xor(lsum0, 32);
  lsum1 += __shfl_xor(lsum1, 16); lsum1 += __shfl_xor(lsum1, 32);
  if (l < 16){ Ss[w][l] = lsum0; Ss[w][16+l] = lsum1; }
  #pragma unroll
  for (int r=0;r<4;r++){
    Os[w][nn][g*4 + r]         = acc00[r];
    Os[w][nn][16 + g*4 + r]    = acc01[r];
    Os[w][16+nn][g*4 + r]      = acc10[r];
    Os[w][16+nn][16 + g*4 + r] = acc11[r];
  }
  __syncthreads();
  float* PO = ws + O_PO + (size_t)(ms*4+b)*131072 + nt*1024;
  for (int i = tid; i < 1024; i += 256){
    int nn2 = i >> 5, c = i & 31;
    PO[i] = Os[0][nn2][c] + Os[1][nn2][c] + Os[2][nn2][c] + Os[3][nn2][c];
  }
  if (tid < 32)
    ws[O_PS + (ms*4+b)*4096 + (nt<<5) + tid] = Ss[0][tid]+Ss[1][tid]+Ss[2][tid]+Ss[3][tid];
}

// ---------------- fused: PAM finalize + CAM energy reduce ----------------
__global__ __launch_bounds__(256) void k_finred(float* __restrict__ ws){
  int bx = blockIdx.x;
  if (bx < 2048){
    int id = bx*256 + threadIdx.x;   // 524288 = (b*4096+n)*32 + c
    int c = id & 31;
    int n = (id >> 5) & 4095;
    int b = id >> 17;
    int pbase = (b*4096 + n)*32 + c;
    int sbase = b*4096 + n;
    float O = ws[O_PO + pbase] + ws[O_PO + 524288 + pbase]
            + ws[O_PO + 1048576 + pbase] + ws[O_PO + 1572864 + pbase];
    float S = ws[O_PS + sbase] + ws[O_PS + 16384 + sbase]
            + ws[O_PS + 32768 + sbase] + ws[O_PS + 49152 + sbase];
    float sa = ws[O_GAM]*(O/S) + ws[O_F1T + id];
    int y = n >> 6, xx = n & 63;
    ((unsigned short*)(ws + O_SAT))[(((size_t)((b*66 + y+1)*66 + xx+1))<<5) + c] = f2b(sa);
    return;
  }
  {
    int id = (bx-2048)*256 + threadIdx.x;   // 4096 = b*1024 + i
    int b = id >> 10, i = id & 1023;
    const float* pe = ws + O_PE + ((size_t)b<<16) + i;
    float s = 0.f;
    #pragma unroll 8
    for (int chk = 0; chk < 64; ++chk) s += pe[chk*1024];
    ws[O_ENE + id] = s;
  }
}

// ---------------- CAM att (in-block) + out -> SC_t ----------------
__global__ __launch_bounds__(256) void k_cam_out(float* __restrict__ ws){
  int blk = blockIdx.x;            // 128
  int b = blk >> 5;
  int chunk = blk & 31;
  int tid = threadIdx.x;
  int half = tid >> 7;             // 0/1
  int nl = tid & 127;
  int n = (chunk << 7) + nl;
  __shared__ float att[32][33];
  if (tid < 32){
    int c = tid;
    const float* e = ws + O_ENE + (b<<10) + (c<<5);
    float M = -1e30f, mn = 1e30f;
    #pragma unroll
    for (int d=0;d<32;d++){ M = fmaxf(M, e[d]); mn = fminf(mn, e[d]); }
    float mx2 = M - mn;
    float s = 0.f, ex[32];
    #pragma unroll
    for (int d=0;d<32;d++){ ex[d] = __expf((M - e[d]) - mx2); s += ex[d]; }
    float inv = 1.f/s;
    #pragma unroll
    for (int d=0;d<32;d++) att[c][d] = ex[d]*inv;
  }
  __syncthreads();
  const float* fp = ws + O_F2T + (((size_t)b<<12) + n)*32;
  float fv[32];
  #pragma unroll
  for (int j=0;j<8;j++){
    float4 v = *(const float4*)(fp + j*4);
    fv[j*4]=v.x; fv[j*4+1]=v.y; fv[j*4+2]=v.z; fv[j*4+3]=v.w;
  }
  float g = ws[O_GAM+1];
  int c0 = half*16;
  unsigned u[8];
  #pragma unroll
  for (int cp=0; cp<8; ++cp){
    int ca = c0 + 2*cp, cb = ca + 1;
    float o0 = 0.f, o1 = 0.f;
    #pragma unroll
    for (int d=0;d<32;d++){ o0 += att[ca][d]*fv[d]; o1 += att[cb][d]*fv[d]; }
    float r0 = g*o0 + fv[ca], r1 = g*o1 + fv[cb];
    u[cp] = (unsigned)f2b(r0) | ((unsigned)f2b(r1) << 16);
  }
  int y = n >> 6, xcol = n & 63;
  unsigned short* sct = (unsigned short*)(ws + O_SCT);
  size_t base = ((size_t)((b*66 + y+1)*66 + xcol+1))*32 + c0;
  *(uint4*)(sct + base)     = make_uint4(u[0],u[1],u[2],u[3]);
  *(uint4*)(sct + base + 8) = make_uint4(u[4],u[5],u[6],u[7]);
}

// ---------------- fused conv51+conv52 (MFMA) + BN/ReLU + sum + 1x1 conv8 + ReLU ----------------
__global__ __launch_bounds__(256) void k_final_mfma(float* __restrict__ ws, float* __restrict__ out){
  int y = blockIdx.x, b = blockIdx.y;          // (64, 4)
  __shared__ unsigned short Bs[2*3*66*40];     // [conv][dy][pix66][k32 pad40]
  __shared__ float ep[2][2][2][16];            // [wavepair][pt][o][pix16]
  int tid = threadIdx.x;
  int w = tid >> 6, l = tid & 63;
  int g = l >> 4, col = l & 15;
  const unsigned short* sat = (const unsigned short*)(ws + O_SAT);
  const unsigned short* sct = (const unsigned short*)(ws + O_SCT);
  for (int i = tid; i < 1584; i += 256){
    int row = i >> 2, part = i & 3;
    int conv = row / 198; int rr = row - conv*198;
    int dy = rr / 66; int pix = rr - dy*66;
    const unsigned short* src = (conv ? sct : sat) + ((size_t)((b*66 + y + dy)*66 + pix))*32 + part*8;
    *(uint4*)&Bs[(size_t)row*40 + part*8] = *(const uint4*)src;
  }
  __syncthreads();
  int cohalf = w & 1, ptbase = (w >> 1) * 2;
  const unsigned short* wp[2] = { (const unsigned short*)(ws + O_W51P), (const unsigned short*)(ws + O_W52P) };
  f32x4 zero = {0.f,0.f,0.f,0.f};
  f32x4 acc[2][2] = {{zero,zero},{zero,zero}};
  for (int dy = 0; dy < 3; ++dy){
    for (int dx = 0; dx < 3; ++dx){
      int tap = dy*3 + dx;
      #pragma unroll
      for (int conv = 0; conv < 2; ++conv){
        bf16x8 af = *(const bf16x8*)(wp[conv] + tap*1024 + (cohalf*16 + col)*32 + g*8);
        #pragma unroll
        for (int pt = 0; pt < 2; ++pt){
          int pix = (ptbase + pt)*16 + col + dx;
          bf16x8 bv = *(const bf16x8*)&Bs[(size_t)((conv*3 + dy)*66 + pix)*40 + g*8];
          acc[conv][pt] = __builtin_amdgcn_mfma_f32_16x16x32_bf16(af, bv, acc[conv][pt], 0, 0, 0);
        }
      }
    }
  }
  float p0[2], p1[2];
  #pragma unroll
  for (int pt = 0; pt < 2; ++pt){
    float s0 = 0.f, s1 = 0.f;
    #pragma unroll
    for (int r = 0; r < 4; ++r){
      int co = cohalf*16 + g*4 + r;
      float A1 = ws[O_BNA + 2*64 + co], B1 = ws[O_BNA + 2*64 + 32 + co];
      float A2 = ws[O_BNA + 3*64 + co], B2 = ws[O_BNA + 3*64 + 32 + co];
      float fs = fmaxf(A1*acc[0][pt][r] + B1, 0.f) + fmaxf(A2*acc[1][pt][r] + B2, 0.f);
      s0 += ws[O_W8 + co]*fs;
      s1 += ws[O_W8 + 32 + co]*fs;
    }
    s0 += __shfl_xor(s0, 16); s0 += __shfl_xor(s0, 32);
    s1 += __shfl_xor(s1, 16); s1 += __shfl_xor(s1, 32);
    p0[pt] = s0; p1[pt] = s1;
  }
  if (cohalf == 0 && l < 16){
    #pragma unroll
    for (int pt = 0; pt < 2; ++pt){ ep[w>>1][pt][0][l] = p0[pt]; ep[w>>1][pt][1][l] = p1[pt]; }
  }
  __syncthreads();
  if (cohalf == 1 && l < 16){
    float b80 = ws[O_W8 + 64], b81 = ws[O_W8 + 65];
    #pragma unroll
    for (int pt = 0; pt < 2; ++pt){
      int pix = y*64 + (w>>1)*32 + pt*16 + l;
      float o0 = p0[pt] + ep[w>>1][pt][0][l] + b80;
      float o1 = p1[pt] + ep[w>>1][pt][1][l] + b81;
      out[((b*2+0)<<12) + pix] = fmaxf(o0, 0.f);
      out[((b*2+1)<<12) + pix] = fmaxf(o1, 0.f);
    }
  }
}

extern "C" void kernel_launch(void* const* d_in, const int* in_sizes, int n_in,
                              void* d_out, int out_size, void* d_ws, size_t ws_size,
                              hipStream_t stream) {
  const float* x    = (const float*)d_in[0];
  float* ws = (float*)d_ws;
  float* out = (float*)d_out;

  k_prep_all<<<1491, 256, 0, stream>>>(
      (const float*)d_in[1], (const float*)d_in[18],
      (const float*)d_in[13], (const float*)d_in[24],
      (const float*)d_in[2],(const float*)d_in[3],(const float*)d_in[4],(const float*)d_in[5],
      (const float*)d_in[19],(const float*)d_in[20],(const float*)d_in[21],(const float*)d_in[22],
      (const float*)d_in[14],(const float*)d_in[15],(const float*)d_in[16],(const float*)d_in[17],
      (const float*)d_in[25],(const float*)d_in[26],(const float*)d_in[27],(const float*)d_in[28],
      (const float*)d_in[29],(const float*)d_in[30],
      (const float*)d_in[6],(const float*)d_in[7],(const float*)d_in[8],(const float*)d_in[9],
      (const float*)d_in[10],(const float*)d_in[11],(const float*)d_in[12],(const float*)d_in[23],
      ws);
  k_nhwc<<<dim3(64,8,4), 256, 0, stream>>>(x, ws);
  k_conv_mfma<<<dim3(256,4), 256, 0, stream>>>(ws);
  k_reduce_feat<<<4129, 256, 0, stream>>>(ws);
  k_qkv_came<<<512, 256, 0, stream>>>(ws);
  k_pam_flash<<<dim3(128,4,4), 256, 0, stream>>>(ws);
  k_finred<<<2064, 256, 0, stream>>>(ws);
  k_cam_out<<<128, 256, 0, stream>>>(ws);
  k_final_mfma<<<dim3(64,4), 256, 0, stream>>>(ws, out);
}

// Round 7
// 95.264 us; speedup vs baseline: 1.7880x; 1.0153x over previous
//
#include <hip/hip_runtime.h>
#include <hip/hip_bf16.h>

// all I/O is float32 (reference is pure jnp.float32)

typedef __attribute__((ext_vector_type(8))) short bf16x8;
typedef __attribute__((ext_vector_type(4))) float f32x4;

// ---- ws layout (f32 element offsets) ----
#define O_WPK   0          // Wpack [tap9][cb16][co64][cin32] bf16 (big convs)
#define O_W51P  147456     // [tap9][co32][ci32] bf16
#define O_W52P  152064
#define O_BNA   156672     // [conv{5a,5c,51,52}][{A,B}][32]
#define O_W8    156928     // w8[2][32], b8 at +64
#define O_PQW   157000     // [4][32], bias at +128
#define O_PKW   157132
#define O_PVW   157264     // [32][32], bias at +1024
#define O_GAM   158320     // p_gamma, c_gamma
#define O_Q     158400     // [b4][cr4][4096] f32
#define O_K     223936     // [b4][cr4][4096] f32
#define O_ENE   453312     // [4][32][32]
#define O_F1T   985792     // [b][4096][32] f32 NHWC
#define O_F2T   1510080    // [b][4096][32] f32 NHWC
#define O_V     2034368    // [b][32][4096] bf16
#define O_SAT   2558656    // [b][66][66][32] bf16 padded  (INSIDE XT overlay!)
#define O_SCT   2837440
// conv-phase overlays (Xt dead after k_conv_mfma):
#define O_XT    461504     // Xt[b4][cb16][66][66][32] bf16 (ends 4922048)
#define O_CP    4922048    // conv partials f32 [ks4][b4][4096pix][64co] (ends 9116352)
// PAM-phase overlays (CP dead after k_feat; XT dead after k_conv_mfma):
#define O_PO    4922048    // PAM partial O [ms4][b4][n4096][c32] f32 (= old CP)
#define O_PS    3116224    // PAM partial S [ms4][b4][n4096] f32 (inside dead XT, after SCT end)
#define O_PE2   9437184    // CAM energy partials [b4][ch128][32][32] f32 (past CP; ws is ~268MB)

__device__ __forceinline__ unsigned short f2b(float f){
  __hip_bfloat16 h = __float2bfloat16(f);
  return *(unsigned short*)&h;
}

// ---------------- fused: NHWC transform + prep (wpack/misc/XT-border zero) ----------------
// nhwc writes XT interior; prep writes XT border + weight buffers: disjoint, mergeable.
// SAT/SCT halo zeroing happens in k_feat (after conv; SAT/SCT live inside XT overlay).
__global__ __launch_bounds__(256) void k_prep_nhwc(
  const float* __restrict__ x,
  const float* w5a, const float* w5c,
  const float* w51, const float* w52,
  const float* s0,const float* b0,const float* m0,const float* v0,
  const float* s1,const float* b1,const float* m1,const float* v1,
  const float* s2,const float* b2,const float* m2,const float* v2,
  const float* s3,const float* b3,const float* m3,const float* v3,
  const float* w8,const float* b8,
  const float* pqw,const float* pqb,const float* pkw,const float* pkb,
  const float* pvw,const float* pvb,const float* pg,const float* cg,
  float* ws)
{
  int bx = blockIdx.x;
  int tid = threadIdx.x;
  __shared__ unsigned short t16[64][65];
  if (bx < 2048){
    // ---- NHWC+pad bf16 transform: Xt[b][cb16][66][66][32]
    int y = bx & 63, ct = (bx >> 6) & 7, b = bx >> 9;
    int r0 = tid >> 4, c0 = (tid & 15) * 4;
    const float* xb = x + ((size_t)(b*512 + ct*64))*4096 + y*64;
    #pragma unroll
    for (int i = 0; i < 4; ++i){
      int row = r0 + i*16;
      float4 v = *(const float4*)(xb + (size_t)row*4096 + c0);
      t16[row][c0+0] = f2b(v.x);
      t16[row][c0+1] = f2b(v.y);
      t16[row][c0+2] = f2b(v.z);
      t16[row][c0+3] = f2b(v.w);
    }
    __syncthreads();
    int pixl = tid >> 2, q = tid & 3;
    unsigned short vs[16];
    #pragma unroll
    for (int j = 0; j < 16; ++j) vs[j] = t16[q*16 + j][pixl];
    unsigned u[8];
    #pragma unroll
    for (int j = 0; j < 8; ++j) u[j] = (unsigned)vs[2*j] | ((unsigned)vs[2*j+1] << 16);
    unsigned short* xt = (unsigned short*)(ws + O_XT);
    int cbl = ct*2 + (q>>1);
    size_t off = (((size_t)(b*16 + cbl)*66 + (y+1))*66 + (pixl+1))*32 + (q&1)*16;
    *(uint4*)(xt + off)     = make_uint4(u[0],u[1],u[2],u[3]);
    *(uint4*)(xt + off + 8) = make_uint4(u[4],u[5],u[6],u[7]);
    return;
  }
  int pbx = bx - 2048;
  if (pbx < 1152){
    int id = pbx*256 + tid;   // 294912
    int tap = id >> 15;
    int r = id & 32767;
    int cb = r >> 11;
    int r2 = r & 2047;
    int co = r2 >> 5, ci = r2 & 31;
    int cin = cb*32 + ci;
    float v = (co < 32) ? w5a[co*4608 + cin*9 + tap] : w5c[(co-32)*4608 + cin*9 + tap];
    ((unsigned short*)ws)[id] = f2b(v);
    return;
  }
  if (pbx < 1231){
    int id = (pbx-1152)*256 + tid;
    if (id >= 20076) return;
    if (id < 9216){ int tap=id>>10, co=(id>>5)&31, ci=id&31;
      ((unsigned short*)(ws + O_W51P))[id] = f2b(w51[co*288 + ci*9 + tap]); return; }
    id -= 9216;
    if (id < 9216){ int tap=id>>10, co=(id>>5)&31, ci=id&31;
      ((unsigned short*)(ws + O_W52P))[id] = f2b(w52[co*288 + ci*9 + tap]); return; }
    id -= 9216;
    if (id < 256){
      int conv = id>>6, ab = (id>>5)&1, c = id&31;
      const float *S,*Bb,*M,*V;
      if (conv==0){S=s0;Bb=b0;M=m0;V=v0;} else if (conv==1){S=s1;Bb=b1;M=m1;V=v1;}
      else if (conv==2){S=s2;Bb=b2;M=m2;V=v2;} else {S=s3;Bb=b3;M=m3;V=v3;}
      float A = S[c] * rsqrtf(V[c] + 1e-5f);
      ws[O_BNA + conv*64 + ab*32 + c] = ab ? (Bb[c] - M[c]*A) : A;
      return; }
    id -= 256;
    if (id < 64){ ws[O_W8+id] = w8[id]; return; } id -= 64;
    if (id < 2){ ws[O_W8+64+id] = b8[id]; return; } id -= 2;
    if (id < 128){ ws[O_PQW+id] = pqw[id]; return; } id -= 128;
    if (id < 4){ ws[O_PQW+128+id] = pqb[id]; return; } id -= 4;
    if (id < 128){ ws[O_PKW+id] = pkw[id]; return; } id -= 128;
    if (id < 4){ ws[O_PKW+128+id] = pkb[id]; return; } id -= 4;
    if (id < 1024){ ws[O_PVW+id] = pvw[id]; return; } id -= 1024;
    if (id < 32){ ws[O_PVW+1024+id] = pvb[id]; return; } id -= 32;
    ws[O_GAM+id] = id ? cg[0] : pg[0];
    return;
  }
  {
    // ---- zero Xt borders (ring of 260 px per (b,cb)) — nhwc writes interior only
    int i = (pbx-1231)*256 + tid;   // 66560 uint4
    if (i >= 66560) return;
    int part = i & 3; int j = i >> 2;
    int rp = j % 260; int bc = j / 260;
    int py, px;
    if (rp < 66){ py = 0; px = rp; }
    else if (rp < 132){ py = 65; px = rp - 66; }
    else if (rp < 196){ py = rp - 131; px = 0; }
    else { py = rp - 195; px = 65; }
    size_t off = (((size_t)bc*66 + py)*66 + px)*32 + part*8;
    *(uint4*)((unsigned short*)(ws + O_XT) + off) = make_uint4(0,0,0,0);
  }
}

// ---------------- big convs as implicit GEMM via MFMA (row-slab staging, reg prefetch) ----------------
__global__ __launch_bounds__(256) void k_conv_mfma(float* __restrict__ ws){
  int mb = blockIdx.x;          // b = mb>>6, y = mb&63
  int ks = blockIdx.y;          // cin quarter (0..3)
  int b = mb >> 6, y = mb & 63;
  __shared__ unsigned short Bs[198*40];   // [dy*66+px][k32 pad40]
  int tid = threadIdx.x;
  int w = tid >> 6, l = tid & 63;
  f32x4 zero = {0.f,0.f,0.f,0.f};
  f32x4 acc[4] = {zero, zero, zero, zero};
  const unsigned short* wp = (const unsigned short*)ws;
  const unsigned short* xt = (const unsigned short*)(ws + O_XT);
  int arow = w*16 + (l & 15);
  int kq = (l >> 4)*8;
  int i0 = tid, i1 = tid + 256, i2 = tid + 512, i3 = tid + 768;  // i3 only if tid<24
  const unsigned short* slab0 = xt + ((size_t)((b*16 + ks*4)*66 + y))*2112;
  uint4 r0 = *(const uint4*)(slab0 + i0*8);
  uint4 r1 = *(const uint4*)(slab0 + i1*8);
  uint4 r2 = *(const uint4*)(slab0 + i2*8);
  uint4 r3 = (tid < 24) ? *(const uint4*)(slab0 + i3*8) : make_uint4(0,0,0,0);
  for (int cb4 = 0; cb4 < 4; ++cb4){
    int cb = ks*4 + cb4;
    __syncthreads();
    *(uint4*)&Bs[(i0>>2)*40 + (i0&3)*8] = r0;
    *(uint4*)&Bs[(i1>>2)*40 + (i1&3)*8] = r1;
    *(uint4*)&Bs[(i2>>2)*40 + (i2&3)*8] = r2;
    if (tid < 24) *(uint4*)&Bs[(i3>>2)*40 + (i3&3)*8] = r3;
    __syncthreads();
    if (cb4 < 3){
      const unsigned short* slab = xt + ((size_t)((b*16 + cb + 1)*66 + y))*2112;
      r0 = *(const uint4*)(slab + i0*8);
      r1 = *(const uint4*)(slab + i1*8);
      r2 = *(const uint4*)(slab + i2*8);
      if (tid < 24) r3 = *(const uint4*)(slab + i3*8);
    }
    #pragma unroll
    for (int tap = 0; tap < 9; ++tap){
      int dy = tap/3, dx = tap - dy*3;
      bf16x8 af = *(const bf16x8*)(wp + (size_t)(tap*16 + cb)*2048 + arow*32 + kq);
      #pragma unroll
      for (int pt = 0; pt < 4; ++pt){
        int pix = pt*16 + (l&15) + dx;
        bf16x8 bv = *(const bf16x8*)&Bs[(dy*66 + pix)*40 + kq];
        acc[pt] = __builtin_amdgcn_mfma_f32_16x16x32_bf16(af, bv, acc[pt], 0, 0, 0);
      }
    }
  }
  float* cp = ws + O_CP + ((size_t)(ks*4 + b))*262144;
  int co0 = w*16 + (l>>4)*4;
  #pragma unroll
  for (int pt = 0; pt < 4; ++pt){
    int pix = y*64 + pt*16 + (l & 15);
    *(f32x4*)&cp[(size_t)pix*64 + co0] = acc[pt];
  }
}

// ---------------- mega-fused: CP reduce + BN/ReLU -> F1T/F2T (+LDS) + qkv + CAM partials
//                  (+ SA/SC halo zero as extra blocks) ----------------
// Block = (b, 32-pixel chunk). F rows kept in LDS -> qkv and CAM energy read LDS, not global.
__global__ __launch_bounds__(256) void k_feat(float* __restrict__ ws){
  int bx = blockIdx.x;
  int tid = threadIdx.x;
  __shared__ float Fl[32][68];               // [pix][co64 +pad]
  __shared__ float wqs[4][32], wks[4][32], wvs[32][32];
  if (bx < 512){
    int b = bx >> 7, chunk = bx & 127;       // 128 chunks of 32 pix
    for (int i = tid; i < 1280; i += 256){
      if (i < 128)      ((float*)wqs)[i]     = ws[O_PQW + i];
      else if (i < 256) ((float*)wks)[i-128] = ws[O_PKW + (i-128)];
      else              ((float*)wvs)[i-256] = ws[O_PVW + (i-256)];
    }
    int pix = tid >> 3, cg = tid & 7;        // 8 co per thread
    int pixg = (chunk << 5) + pix;
    const float* cpb = ws + O_CP + (size_t)b*262144 + (size_t)pixg*64 + cg*8;
    f32x4 sa_ = *(const f32x4*)(cpb);
    f32x4 sb_ = *(const f32x4*)(cpb + 4);
    {
      f32x4 t0 = *(const f32x4*)(cpb + 1048576);
      f32x4 t1 = *(const f32x4*)(cpb + 1048576 + 4);
      f32x4 t2 = *(const f32x4*)(cpb + 2097152);
      f32x4 t3 = *(const f32x4*)(cpb + 2097152 + 4);
      f32x4 t4 = *(const f32x4*)(cpb + 3145728);
      f32x4 t5 = *(const f32x4*)(cpb + 3145728 + 4);
      sa_ = (sa_ + t0) + (t2 + t4);
      sb_ = (sb_ + t1) + (t3 + t5);
    }
    int co0 = cg*8;
    int conv = co0 >> 5, cc0 = co0 & 31;     // 8-group never straddles conv boundary
    float v8[8];
    #pragma unroll
    for (int j = 0; j < 8; ++j){
      int c = cc0 + j;
      float A = ws[O_BNA + conv*64 + c], Bb = ws[O_BNA + conv*64 + 32 + c];
      float s = (j < 4) ? sa_[j] : sb_[j-4];
      v8[j] = fmaxf(A*s + Bb, 0.f);
    }
    float* fdst = ws + (conv == 0 ? O_F1T : O_F2T) + ((size_t)(b*4096 + pixg))*32 + cc0;
    *(f32x4*)(fdst)     = (f32x4){v8[0],v8[1],v8[2],v8[3]};
    *(f32x4*)(fdst + 4) = (f32x4){v8[4],v8[5],v8[6],v8[7]};
    *(f32x4*)&Fl[pix][co0]     = (f32x4){v8[0],v8[1],v8[2],v8[3]};
    *(f32x4*)&Fl[pix][co0 + 4] = (f32x4){v8[4],v8[5],v8[6],v8[7]};
    __syncthreads();
    // ---- qkv phase (threads 0..127): part, pixel
    if (tid < 128){
      int part = tid >> 5, pixl = tid & 31;
      int n = (chunk << 5) + pixl;
      float fv[32];
      #pragma unroll
      for (int c = 0; c < 32; ++c) fv[c] = Fl[pixl][c];
      float q = ws[O_PQW+128+part], k = ws[O_PKW+128+part];
      #pragma unroll
      for (int c = 0; c < 32; ++c){ q += wqs[part][c]*fv[c]; k += wks[part][c]*fv[c]; }
      ws[O_Q + (((b<<2)+part)<<12) + n] = q;
      ws[O_K + (((b<<2)+part)<<12) + n] = k;
      unsigned short* vbp = (unsigned short*)(ws + O_V);
      #pragma unroll
      for (int j2 = 0; j2 < 8; ++j2){
        int c2 = part*8 + j2;
        float v = ws[O_PVW+1024+c2];
        #pragma unroll
        for (int c = 0; c < 32; ++c) v += wvs[c2][c]*fv[c];
        vbp[(((b<<5)+c2)<<12) + n] = f2b(v);
      }
    }
    // ---- CAM energy partial phase (all 256 threads), F2 = Fl[:,32..63]
    {
      int ce = tid >> 3, d0 = (tid & 7) * 4;
      float a0=0.f, a1=0.f, a2=0.f, a3=0.f;
      #pragma unroll 8
      for (int n = 0; n < 32; ++n){
        float fc = Fl[n][32 + ce];
        float f0 = Fl[n][32 + d0], f1 = Fl[n][32 + d0 + 1];
        float f2 = Fl[n][32 + d0 + 2], f3 = Fl[n][32 + d0 + 3];
        a0 = fmaf(fc, f0, a0); a1 = fmaf(fc, f1, a1);
        a2 = fmaf(fc, f2, a2); a3 = fmaf(fc, f3, a3);
      }
      float* pe = ws + O_PE2 + ((size_t)(b*128 + chunk))*1024 + ce*32 + d0;
      *(f32x4*)pe = (f32x4){a0, a1, a2, a3};
    }
    return;
  }
  {
    // ---- zero SA_t / SC_t borders (after conv: XT dead, zeros survive)
    int i = (bx-512)*256 + tid;   // 8320 uint4
    if (i >= 8320) return;
    int part = i & 3; int j = i >> 2;
    int arr = j / 1040; int rem = j - arr*1040;
    int b = rem / 260; int rp = rem % 260;
    int py, px;
    if (rp < 66){ py = 0; px = rp; }
    else if (rp < 132){ py = 65; px = rp - 66; }
    else if (rp < 196){ py = rp - 131; px = 0; }
    else { py = rp - 195; px = 65; }
    size_t off = (((size_t)(b*66) + py)*66 + px)*32 + part*8;
    unsigned short* base = (unsigned short*)(ws + O_SAT + arr*278784);
    *(uint4*)(base + off) = make_uint4(0,0,0,0);
  }
}

// ---------------- PAM flash, 32-n tiles, m-split x4, V direct-to-register ----------------
__global__ __launch_bounds__(256, 6) void k_pam_flash(float* __restrict__ ws){
  int nt = blockIdx.x;   // 0..127 n-tile of 32
  int b  = blockIdx.y;   // 0..3
  int ms = blockIdx.z;   // 0..3 m-split
  __shared__ float Ks[2][4][4][32];    // [buf][wave][cr][m32]  4 KB
  __shared__ float Ss[4][32];
  __shared__ float Os[4][32][36];      // 18 KB
  int tid = threadIdx.x;
  int w = tid >> 6, l = tid & 63;
  int nn = l & 15, g = l >> 4;
  int n0 = (nt<<5) + nn;
  const float LOG2E = 1.44269504f;
  const float BIAS  = -28.8539008f;   // -20*log2(e); fixed shift, energies O(+-35)
  float q0[4], q1[4];
  #pragma unroll
  for (int cr=0;cr<4;++cr){
    q0[cr] = ws[O_Q + (((b<<2)+cr)<<12) + n0] * LOG2E;
    q1[cr] = ws[O_Q + (((b<<2)+cr)<<12) + n0 + 16] * LOG2E;
  }
  int e0i = l*2, cr_s = e0i >> 5, mm_s = e0i & 31;
  int mbase = ms*1024 + w*256;        // wave owns m in [mbase, mbase+256), 8 chunks
  const float* ksrc = ws + O_K + (((b<<2)+cr_s)<<12) + mbase + mm_s;
  const unsigned short* vb = (const unsigned short*)(ws + O_V);
  int mo = g*8;
  const unsigned short* vp0 = vb + (((b<<5) + nn)<<12) + mbase + mo;
  const unsigned short* vp1 = vb + (((b<<5) + 16 + nn)<<12) + mbase + mo;
  f32x4 zero = {0.f,0.f,0.f,0.f};
  f32x4 acc00 = zero, acc01 = zero, acc10 = zero, acc11 = zero;
  float lsum0 = 0.f, lsum1 = 0.f;
  bf16x8 a0A = *(const bf16x8*)(vp0);
  bf16x8 a1A = *(const bf16x8*)(vp1);
  float2 kreg = *(const float2*)(ksrc);
  *(float2*)&Ks[0][w][cr_s][mm_s] = kreg;
  bf16x8 a0B, a1B;
  for (int ch = 0; ch < 8; ++ch){
    int buf = ch & 1;
    if (ch < 7){
      int mn = (ch+1)*32;
      a0B = *(const bf16x8*)(vp0 + mn);
      a1B = *(const bf16x8*)(vp1 + mn);
      kreg = *(const float2*)(ksrc + mn);
    }
    float e0[8], e1[8];
    {
      float4 ka, kb;
      ka = *(const float4*)&Ks[buf][w][0][mo];
      kb = *(const float4*)&Ks[buf][w][0][mo+4];
      e0[0]=fmaf(q0[0],ka.x,BIAS); e0[1]=fmaf(q0[0],ka.y,BIAS); e0[2]=fmaf(q0[0],ka.z,BIAS); e0[3]=fmaf(q0[0],ka.w,BIAS);
      e0[4]=fmaf(q0[0],kb.x,BIAS); e0[5]=fmaf(q0[0],kb.y,BIAS); e0[6]=fmaf(q0[0],kb.z,BIAS); e0[7]=fmaf(q0[0],kb.w,BIAS);
      e1[0]=fmaf(q1[0],ka.x,BIAS); e1[1]=fmaf(q1[0],ka.y,BIAS); e1[2]=fmaf(q1[0],ka.z,BIAS); e1[3]=fmaf(q1[0],ka.w,BIAS);
      e1[4]=fmaf(q1[0],kb.x,BIAS); e1[5]=fmaf(q1[0],kb.y,BIAS); e1[6]=fmaf(q1[0],kb.z,BIAS); e1[7]=fmaf(q1[0],kb.w,BIAS);
#define KACC(CR) \
      ka = *(const float4*)&Ks[buf][w][CR][mo]; \
      kb = *(const float4*)&Ks[buf][w][CR][mo+4]; \
      e0[0]=fmaf(q0[CR],ka.x,e0[0]); e0[1]=fmaf(q0[CR],ka.y,e0[1]); e0[2]=fmaf(q0[CR],ka.z,e0[2]); e0[3]=fmaf(q0[CR],ka.w,e0[3]); \
      e0[4]=fmaf(q0[CR],kb.x,e0[4]); e0[5]=fmaf(q0[CR],kb.y,e0[5]); e0[6]=fmaf(q0[CR],kb.z,e0[6]); e0[7]=fmaf(q0[CR],kb.w,e0[7]); \
      e1[0]=fmaf(q1[CR],ka.x,e1[0]); e1[1]=fmaf(q1[CR],ka.y,e1[1]); e1[2]=fmaf(q1[CR],ka.z,e1[2]); e1[3]=fmaf(q1[CR],ka.w,e1[3]); \
      e1[4]=fmaf(q1[CR],kb.x,e1[4]); e1[5]=fmaf(q1[CR],kb.y,e1[5]); e1[6]=fmaf(q1[CR],kb.z,e1[6]); e1[7]=fmaf(q1[CR],kb.w,e1[7]);
      KACC(1)
      KACC(2)
      KACC(3)
#undef KACC
    }
    union { bf16x8 v; unsigned short u[8]; } pb0, pb1;
    #pragma unroll
    for (int j=0;j<8;j++){ float p = __builtin_amdgcn_exp2f(e0[j]); lsum0 += p; pb0.u[j] = f2b(p); }
    #pragma unroll
    for (int j=0;j<8;j++){ float p = __builtin_amdgcn_exp2f(e1[j]); lsum1 += p; pb1.u[j] = f2b(p); }
    acc00 = __builtin_amdgcn_mfma_f32_16x16x32_bf16(a0A, pb0.v, acc00, 0, 0, 0);
    acc01 = __builtin_amdgcn_mfma_f32_16x16x32_bf16(a1A, pb0.v, acc01, 0, 0, 0);
    acc10 = __builtin_amdgcn_mfma_f32_16x16x32_bf16(a0A, pb1.v, acc10, 0, 0, 0);
    acc11 = __builtin_amdgcn_mfma_f32_16x16x32_bf16(a1A, pb1.v, acc11, 0, 0, 0);
    if (ch < 7){
      int nb = buf ^ 1;
      *(float2*)&Ks[nb][w][cr_s][mm_s] = kreg;
      a0A = a0B; a1A = a1B;
    }
  }
  lsum0 += __shfl_xor(lsum0, 16); lsum0 += __shfl_xor(lsum0, 32);
  lsum1 += __shfl_xor(lsum1, 16); lsum1 += __shfl_xor(lsum1, 32);
  if (l < 16){ Ss[w][l] = lsum0; Ss[w][16+l] = lsum1; }
  #pragma unroll
  for (int r=0;r<4;r++){
    Os[w][nn][g*4 + r]         = acc00[r];
    Os[w][nn][16 + g*4 + r]    = acc01[r];
    Os[w][16+nn][g*4 + r]      = acc10[r];
    Os[w][16+nn][16 + g*4 + r] = acc11[r];
  }
  __syncthreads();
  float* PO = ws + O_PO + (size_t)(ms*4+b)*131072 + nt*1024;
  for (int i = tid; i < 1024; i += 256){
    int nn2 = i >> 5, c = i & 31;
    PO[i] = Os[0][nn2][c] + Os[1][nn2][c] + Os[2][nn2][c] + Os[3][nn2][c];
  }
  if (tid < 32)
    ws[O_PS + (ms*4+b)*4096 + (nt<<5) + tid] = Ss[0][tid]+Ss[1][tid]+Ss[2][tid]+Ss[3][tid];
}

// ---------------- fused: PAM finalize (vectorized, 4 ch/thread) + CAM energy reduce ----------------
__global__ __launch_bounds__(256) void k_finred(float* __restrict__ ws){
  int bx = blockIdx.x;
  int tid = threadIdx.x;
  if (bx < 512){
    int id = bx*256 + tid;   // 131072 = (b, n, c-quad)
    int cq = (id & 7) * 4;
    int n  = (id >> 3) & 4095;
    int b  = id >> 15;
    size_t pbase = (size_t)(b*4096 + n)*32 + cq;
    int sbase = b*4096 + n;
    f32x4 O = *(const f32x4*)(ws + O_PO + pbase);
    O = O + *(const f32x4*)(ws + O_PO + 524288 + pbase);
    O = O + *(const f32x4*)(ws + O_PO + 1048576 + pbase);
    O = O + *(const f32x4*)(ws + O_PO + 1572864 + pbase);
    float S = ws[O_PS + sbase] + ws[O_PS + 16384 + sbase]
            + ws[O_PS + 32768 + sbase] + ws[O_PS + 49152 + sbase];
    float gam = ws[O_GAM];
    f32x4 f1 = *(const f32x4*)(ws + O_F1T + (size_t)id*4);
    unsigned short h[4];
    #pragma unroll
    for (int j = 0; j < 4; ++j) h[j] = f2b(gam*(O[j]/S) + f1[j]);
    int y = n >> 6, xx = n & 63;
    unsigned short* sat = (unsigned short*)(ws + O_SAT);
    uint2 u; u.x = (unsigned)h[0] | ((unsigned)h[1] << 16);
             u.y = (unsigned)h[2] | ((unsigned)h[3] << 16);
    *(uint2*)&sat[(((size_t)((b*66 + y+1)*66 + xx+1))<<5) + cq] = u;
    return;
  }
  {
    int id = (bx-512)*256 + tid;   // 4096 = b*1024 + i
    int b = id >> 10, i = id & 1023;
    const float* pe = ws + O_PE2 + ((size_t)b)*131072 + i;
    float s = 0.f;
    #pragma unroll 8
    for (int chk = 0; chk < 128; ++chk) s += pe[chk*1024];
    ws[O_ENE + id] = s;
  }
}

// ---------------- CAM att (in-block) + out -> SC_t ----------------
__global__ __launch_bounds__(256) void k_cam_out(float* __restrict__ ws){
  int blk = blockIdx.x;            // 128
  int b = blk >> 5;
  int chunk = blk & 31;
  int tid = threadIdx.x;
  int half = tid >> 7;             // 0/1
  int nl = tid & 127;
  int n = (chunk << 7) + nl;
  __shared__ float att[32][33];
  if (tid < 32){
    int c = tid;
    const float* e = ws + O_ENE + (b<<10) + (c<<5);
    float M = -1e30f, mn = 1e30f;
    #pragma unroll
    for (int d=0;d<32;d++){ M = fmaxf(M, e[d]); mn = fminf(mn, e[d]); }
    float mx2 = M - mn;
    float s = 0.f, ex[32];
    #pragma unroll
    for (int d=0;d<32;d++){ ex[d] = __expf((M - e[d]) - mx2); s += ex[d]; }
    float inv = 1.f/s;
    #pragma unroll
    for (int d=0;d<32;d++) att[c][d] = ex[d]*inv;
  }
  __syncthreads();
  const float* fp = ws + O_F2T + (((size_t)b<<12) + n)*32;
  float fv[32];
  #pragma unroll
  for (int j=0;j<8;j++){
    float4 v = *(const float4*)(fp + j*4);
    fv[j*4]=v.x; fv[j*4+1]=v.y; fv[j*4+2]=v.z; fv[j*4+3]=v.w;
  }
  float g = ws[O_GAM+1];
  int c0 = half*16;
  unsigned u[8];
  #pragma unroll
  for (int cp=0; cp<8; ++cp){
    int ca = c0 + 2*cp, cb = ca + 1;
    float o0 = 0.f, o1 = 0.f;
    #pragma unroll
    for (int d=0;d<32;d++){ o0 += att[ca][d]*fv[d]; o1 += att[cb][d]*fv[d]; }
    float r0 = g*o0 + fv[ca], r1 = g*o1 + fv[cb];
    u[cp] = (unsigned)f2b(r0) | ((unsigned)f2b(r1) << 16);
  }
  int y = n >> 6, xcol = n & 63;
  unsigned short* sct = (unsigned short*)(ws + O_SCT);
  size_t base = ((size_t)((b*66 + y+1)*66 + xcol+1))*32 + c0;
  *(uint4*)(sct + base)     = make_uint4(u[0],u[1],u[2],u[3]);
  *(uint4*)(sct + base + 8) = make_uint4(u[4],u[5],u[6],u[7]);
}

// ---------------- fused conv51+conv52 (MFMA) + BN/ReLU + sum + 1x1 conv8 + ReLU ----------------
__global__ __launch_bounds__(256) void k_final_mfma(float* __restrict__ ws, float* __restrict__ out){
  int y = blockIdx.x, b = blockIdx.y;          // (64, 4)
  __shared__ unsigned short Bs[2*3*66*40];     // [conv][dy][pix66][k32 pad40]
  __shared__ float ep[2][2][2][16];            // [wavepair][pt][o][pix16]
  int tid = threadIdx.x;
  int w = tid >> 6, l = tid & 63;
  int g = l >> 4, col = l & 15;
  const unsigned short* sat = (const unsigned short*)(ws + O_SAT);
  const unsigned short* sct = (const unsigned short*)(ws + O_SCT);
  for (int i = tid; i < 1584; i += 256){
    int row = i >> 2, part = i & 3;
    int conv = row / 198; int rr = row - conv*198;
    int dy = rr / 66; int pix = rr - dy*66;
    const unsigned short* src = (conv ? sct : sat) + ((size_t)((b*66 + y + dy)*66 + pix))*32 + part*8;
    *(uint4*)&Bs[(size_t)row*40 + part*8] = *(const uint4*)src;
  }
  __syncthreads();
  int cohalf = w & 1, ptbase = (w >> 1) * 2;
  const unsigned short* wp[2] = { (const unsigned short*)(ws + O_W51P), (const unsigned short*)(ws + O_W52P) };
  f32x4 zero = {0.f,0.f,0.f,0.f};
  f32x4 acc[2][2] = {{zero,zero},{zero,zero}};
  for (int dy = 0; dy < 3; ++dy){
    for (int dx = 0; dx < 3; ++dx){
      int tap = dy*3 + dx;
      #pragma unroll
      for (int conv = 0; conv < 2; ++conv){
        bf16x8 af = *(const bf16x8*)(wp[conv] + tap*1024 + (cohalf*16 + col)*32 + g*8);
        #pragma unroll
        for (int pt = 0; pt < 2; ++pt){
          int pix = (ptbase + pt)*16 + col + dx;
          bf16x8 bv = *(const bf16x8*)&Bs[(size_t)((conv*3 + dy)*66 + pix)*40 + g*8];
          acc[conv][pt] = __builtin_amdgcn_mfma_f32_16x16x32_bf16(af, bv, acc[conv][pt], 0, 0, 0);
        }
      }
    }
  }
  float p0[2], p1[2];
  #pragma unroll
  for (int pt = 0; pt < 2; ++pt){
    float s0 = 0.f, s1 = 0.f;
    #pragma unroll
    for (int r = 0; r < 4; ++r){
      int co = cohalf*16 + g*4 + r;
      float A1 = ws[O_BNA + 2*64 + co], B1 = ws[O_BNA + 2*64 + 32 + co];
      float A2 = ws[O_BNA + 3*64 + co], B2 = ws[O_BNA + 3*64 + 32 + co];
      float fs = fmaxf(A1*acc[0][pt][r] + B1, 0.f) + fmaxf(A2*acc[1][pt][r] + B2, 0.f);
      s0 += ws[O_W8 + co]*fs;
      s1 += ws[O_W8 + 32 + co]*fs;
    }
    s0 += __shfl_xor(s0, 16); s0 += __shfl_xor(s0, 32);
    s1 += __shfl_xor(s1, 16); s1 += __shfl_xor(s1, 32);
    p0[pt] = s0; p1[pt] = s1;
  }
  if (cohalf == 0 && l < 16){
    #pragma unroll
    for (int pt = 0; pt < 2; ++pt){ ep[w>>1][pt][0][l] = p0[pt]; ep[w>>1][pt][1][l] = p1[pt]; }
  }
  __syncthreads();
  if (cohalf == 1 && l < 16){
    float b80 = ws[O_W8 + 64], b81 = ws[O_W8 + 65];
    #pragma unroll
    for (int pt = 0; pt < 2; ++pt){
      int pix = y*64 + (w>>1)*32 + pt*16 + l;
      float o0 = p0[pt] + ep[w>>1][pt][0][l] + b80;
      float o1 = p1[pt] + ep[w>>1][pt][1][l] + b81;
      out[((b*2+0)<<12) + pix] = fmaxf(o0, 0.f);
      out[((b*2+1)<<12) + pix] = fmaxf(o1, 0.f);
    }
  }
}

extern "C" void kernel_launch(void* const* d_in, const int* in_sizes, int n_in,
                              void* d_out, int out_size, void* d_ws, size_t ws_size,
                              hipStream_t stream) {
  const float* x    = (const float*)d_in[0];
  float* ws = (float*)d_ws;
  float* out = (float*)d_out;

  k_prep_nhwc<<<3539, 256, 0, stream>>>(
      x,
      (const float*)d_in[1], (const float*)d_in[18],
      (const float*)d_in[13], (const float*)d_in[24],
      (const float*)d_in[2],(const float*)d_in[3],(const float*)d_in[4],(const float*)d_in[5],
      (const float*)d_in[19],(const float*)d_in[20],(const float*)d_in[21],(const float*)d_in[22],
      (const float*)d_in[14],(const float*)d_in[15],(const float*)d_in[16],(const float*)d_in[17],
      (const float*)d_in[25],(const float*)d_in[26],(const float*)d_in[27],(const float*)d_in[28],
      (const float*)d_in[29],(const float*)d_in[30],
      (const float*)d_in[6],(const float*)d_in[7],(const float*)d_in[8],(const float*)d_in[9],
      (const float*)d_in[10],(const float*)d_in[11],(const float*)d_in[12],(const float*)d_in[23],
      ws);
  k_conv_mfma<<<dim3(256,4), 256, 0, stream>>>(ws);
  k_feat<<<545, 256, 0, stream>>>(ws);
  k_pam_flash<<<dim3(128,4,4), 256, 0, stream>>>(ws);
  k_finred<<<528, 256, 0, stream>>>(ws);
  k_cam_out<<<128, 256, 0, stream>>>(ws);
  k_final_mfma<<<dim3(64,4), 256, 0, stream>>>(ws, out);
}